// Round 12
// baseline (1238.858 us; speedup 1.0000x reference)
//
#include <hip/hip_runtime.h>
#include <math.h>

#define HDIM 256
#define NHEADS 8
#define NEG 0.2f
#define NB 256  // edge-partition blocks for CSR build
#define SEG 4   // attention edge-list segments per node

typedef float f32x4 __attribute__((ext_vector_type(4)));
typedef _Float16 f16x8 __attribute__((ext_vector_type(8)));
typedef __fp16 fp16v2 __attribute__((ext_vector_type(2)));

#define AGENT __HIP_MEMORY_SCOPE_AGENT

// ---------------- CSR build, phase A: per-block LDS-privatized histograms ----
__global__ __launch_bounds__(256) void edge_part(
    const int* __restrict__ ei, const float* __restrict__ ea, int E, int CH,
    int* __restrict__ pcnt, float* __restrict__ psum, int* __restrict__ pcol) {
  __shared__ int   lcnt[512];
  __shared__ float ls0[512], ls1[512], ls2[512];
  __shared__ int   lcol[1024];
  int t = threadIdx.x, b = blockIdx.x;
  for (int n = t; n < 512; n += 256) {
    lcnt[n] = 0; ls0[n] = 0.f; ls1[n] = 0.f; ls2[n] = 0.f;
    lcol[n] = 0; lcol[512 + n] = 0;
  }
  __syncthreads();
  int e0 = b * CH, e1 = min(E, e0 + CH);
  for (int e = e0 + t; e < e1; e += 256) {
    int src = ei[e], dst = ei[E + e];
    float a0 = ea[3*e], a1 = ea[3*e+1], a2 = ea[3*e+2];
    atomicAdd(&lcnt[dst], 1);
    atomicAdd(&ls0[dst], a0);
    atomicAdd(&ls1[dst], a1);
    atomicAdd(&ls2[dst], a2);
    int idx = 0; float best = a0;
    if (a1 > best) { best = a1; idx = 1; }
    if (a2 > best) { idx = 2; }
    if (idx) {
      int o = (idx - 1) << 9;   // 0 or 512
      atomicAdd(&lcol[o + src], 1);
      atomicAdd(&lcol[o + dst], 1);
    }
  }
  __syncthreads();
  for (int n = t; n < 512; n += 256) {
    pcnt[b*512 + n] = lcnt[n];
    psum[(size_t)(0*NB + b)*512 + n] = ls0[n];
    psum[(size_t)(1*NB + b)*512 + n] = ls1[n];
    psum[(size_t)(2*NB + b)*512 + n] = ls2[n];
    pcol[(size_t)(0*NB + b)*512 + n] = lcol[n];
    pcol[(size_t)(1*NB + b)*512 + n] = lcol[512 + n];
  }
}

// ---------------- CSR build, phase B1: parallel partial reduction ------------
__global__ __launch_bounds__(256) void red_kernel(
    const int* __restrict__ pcnt, const float* __restrict__ psum,
    const int* __restrict__ pcol,
    int* __restrict__ cnt, float* __restrict__ sred, int* __restrict__ dred,
    int* __restrict__ pbase) {
  int q = blockIdx.x >> 1;
  int n = (blockIdx.x & 1)*256 + threadIdx.x;
  if (q == 0) {
    int run = 0;
#pragma unroll 8
    for (int b = 0; b < NB; ++b) {
      int v = pcnt[b*512 + n];
      pbase[b*512 + n] = run;
      run += v;
    }
    cnt[n] = run;
  } else if (q <= 3) {
    int qq = q - 1;
    float s = 0.f;
#pragma unroll 8
    for (int b = 0; b < NB; ++b) s += psum[(size_t)(qq*NB + b)*512 + n];
    sred[qq*512 + n] = s;
  } else {
    int qq = q - 4;
    int s = 0;
#pragma unroll 8
    for (int b = 0; b < NB; ++b) s += pcol[(size_t)(qq*NB + b)*512 + n];
    dred[qq*512 + n] = s;
  }
}

// ---------------- CSR build, phase B2: scan + self-loops + energy ------------
__global__ __launch_bounds__(512) void scan2(
    const int* __restrict__ cnt, const float* __restrict__ sred,
    const int* __restrict__ dred, int N,
    int* __restrict__ rowp, float4* __restrict__ csr,
    const float* __restrict__ coupling, float* __restrict__ eout) {
  int t = threadIdx.x;
  int c = (t < N) ? cnt[t] : 0;
  __shared__ int sbuf[512];
  int v = (t < N) ? (c + 1) : 0;    // +1 self-loop slot
  sbuf[t] = v;
  __syncthreads();
  for (int off = 1; off < 512; off <<= 1) {
    int add = (t >= off) ? sbuf[t - off] : 0;
    __syncthreads();
    sbuf[t] += add;
    __syncthreads();
  }
  int incl = sbuf[t], excl = incl - v;
  if (t < N) {
    rowp[t] = excl;
    if (t == N - 1) rowp[N] = incl;
    float inv = 1.f / fmaxf((float)c, 1.f);
    csr[excl] = make_float4(sred[t]*inv, sred[512 + t]*inv, sred[1024 + t]*inv,
                            __int_as_float(t));
  }
  // Potts energy from color-degree counts
  float e = 0.f;
  if (t < N) {
    float d1 = (float)dred[t], d2 = (float)dred[512 + t];
    e = d1*d1 + d2*d2;
  }
#pragma unroll
  for (int off = 1; off < 64; off <<= 1) e += __shfl_xor(e, off);
  __shared__ float wred[8];
  if ((t & 63) == 0) wred[t >> 6] = e;
  __syncthreads();
  if (t == 0) {
    float s = 0.f;
#pragma unroll
    for (int i = 0; i < 8; ++i) s += wred[i];
    eout[0] = coupling[0] * s / (2.f * (float)N);
  }
}

// ---------------- CSR build, phase C: scatter via LDS slot counters ----------
__global__ __launch_bounds__(256) void scatter2(
    const int* __restrict__ ei, const float* __restrict__ ea, int E, int CH,
    const int* __restrict__ rowp, const int* __restrict__ pbase,
    float4* __restrict__ csr) {
  __shared__ int lofs[512];
  int t = threadIdx.x, b = blockIdx.x;
  for (int n = t; n < 512; n += 256) lofs[n] = 0;
  __syncthreads();
  int e0 = b * CH, e1 = min(E, e0 + CH);
  for (int e = e0 + t; e < e1; e += 256) {
    int src = ei[e], dst = ei[E + e];
    float a0 = ea[3*e], a1 = ea[3*e+1], a2 = ea[3*e+2];
    int lp = atomicAdd(&lofs[dst], 1);
    int pos = rowp[dst] + 1 + pbase[b*512 + dst] + lp;
    csr[pos] = make_float4(a0, a1, a2, __int_as_float(src));
  }
}

// ---------------- weight prep: 10x[256x256] + W2[256x128] + zero counters ----
__global__ __launch_bounds__(256) void w_prep_all(
    const float* __restrict__ Wl, const float* __restrict__ Wr,
    const float* __restrict__ p1W, const float* __restrict__ W2,
    unsigned short* __restrict__ dst, unsigned short* __restrict__ W2h,
    int* __restrict__ ctr, int* __restrict__ vctr) {
  int gid = blockIdx.x * 256 + threadIdx.x;   // 10*65536 + 32768
  if (gid < 4*512 + 1) {                      // zero layer counters + value ctr
    if (gid < 4*512) ctr[gid] = 0; else vctr[0] = 0;
  }
  if (gid < 10*65536) {
    int s = gid >> 16, e = gid & 65535;
    int k = e >> 8, n = e & 255;
    const float* src = (s < 4) ? (Wl + (size_t)s*65536)
                     : (s < 8) ? (Wr + (size_t)(s-4)*65536)
                               : (p1W + (size_t)(s-8)*65536);
    int c = k >> 5, quad = (k >> 3) & 3, kj = k & 7;
    int nt = n >> 4, nl = n & 15;
    int lane = quad*16 + nl;
    _Float16 hv = (_Float16)src[(size_t)k*256 + n];
    dst[(size_t)s*65536 + ((nt*8 + c)*512 + lane*8 + kj)] = *(unsigned short*)&hv;
  } else {
    int e = gid - 10*65536;                   // 32768 W2 elems (pair head)
    int k = e >> 7, n = e & 127;
    int c = k >> 5, kq = (k >> 3) & 3, kj = k & 7;
    int nt = n >> 4, nl = n & 15;
    int lane = kq*16 + nl;
    _Float16 hv = (_Float16)W2[(size_t)k*128 + n];
    W2h[(size_t)(((c*8 + nt)*64 + lane)*8 + kj)] = *(unsigned short*)&hv;
  }
}

// ---------------- dual GEMM via MFMA: o1 = h@W1+b1, o2 = h@W2+b2 -------------
// Hm==nullptr -> h computed on the fly as x*embW+embb (layer 0).
__global__ __launch_bounds__(256) void dual_gemm_mfma(
    const float* __restrict__ Hm,
    const float* __restrict__ x, const float* __restrict__ embW,
    const float* __restrict__ embb,
    const unsigned short* __restrict__ W1h, const unsigned short* __restrict__ W2h,
    const float* __restrict__ b1, const float* __restrict__ b2,
    float* __restrict__ o1, float* __restrict__ o2,
    unsigned short* __restrict__ o1h) {
  int bx = blockIdx.x, by = blockIdx.y;
  int t = threadIdx.x, w = t >> 6, l = t & 63;
  int quad = l >> 4, nl = l & 15;
  int mt = bx*4 + w;

  const unsigned short* Wh; const float* bias; float* o; int nt;
  bool first = (by < 16);
  if (first) { Wh = W1h; bias = b1; o = o1; nt = by; }
  else       { Wh = W2h; bias = b2; o = o2; nt = by - 16; }

  int row = mt*16 + nl;
  const float* Ar = Hm ? (Hm + (size_t)row*HDIM + quad*8) : nullptr;
  float xm = Hm ? 0.f : x[row];
  f32x4 acc = (f32x4){0.f, 0.f, 0.f, 0.f};

#pragma unroll
  for (int c = 0; c < 8; ++c) {
    float4 a0, a1;
    if (Hm) {
      a0 = *(const float4*)(Ar + c*32);
      a1 = *(const float4*)(Ar + c*32 + 4);
    } else {
      int kb = c*32 + quad*8;
      float4 e0 = *(const float4*)(embW + kb);
      float4 e1 = *(const float4*)(embW + kb + 4);
      float4 c0 = *(const float4*)(embb + kb);
      float4 c1 = *(const float4*)(embb + kb + 4);
      a0 = make_float4(fmaf(xm, e0.x, c0.x), fmaf(xm, e0.y, c0.y),
                       fmaf(xm, e0.z, c0.z), fmaf(xm, e0.w, c0.w));
      a1 = make_float4(fmaf(xm, e1.x, c1.x), fmaf(xm, e1.y, c1.y),
                       fmaf(xm, e1.z, c1.z), fmaf(xm, e1.w, c1.w));
    }
    union { f16x8 v8; fp16v2 v2[4]; } u;
    u.v2[0] = __builtin_amdgcn_cvt_pkrtz(a0.x, a0.y);
    u.v2[1] = __builtin_amdgcn_cvt_pkrtz(a0.z, a0.w);
    u.v2[2] = __builtin_amdgcn_cvt_pkrtz(a1.x, a1.y);
    u.v2[3] = __builtin_amdgcn_cvt_pkrtz(a1.z, a1.w);
    f16x8 bfrag = *(const f16x8*)(Wh + (size_t)((nt*8 + c)*512 + l*8));
    acc = __builtin_amdgcn_mfma_f32_16x16x32_f16(u.v8, bfrag, acc, 0, 0, 0);
  }

  int colg = nt*16 + nl;
  float bv = bias ? bias[colg] : 0.f;
#pragma unroll
  for (int r = 0; r < 4; ++r) {
    float val = acc[r] + bv;
    size_t idx = (size_t)(mt*16 + quad*4 + r)*HDIM + colg;
    o[idx] = val;
    if (first && o1h) {
      _Float16 hv = (_Float16)val;
      o1h[idx] = *(unsigned short*)&hv;
    }
  }
}

// ---------------- GATv2 attention: fused gather + last-block merge -----------
// grid N*SEG; each block computes one segment's online-softmax partial, then
// the last-arriving block per node merges + residual + LayerNorm (agent-scope
// atomics for cross-XCD coherence).
__global__ __launch_bounds__(256) void attn_fused(
    const unsigned short* __restrict__ xlh, const float* __restrict__ xr,
    const float4* __restrict__ csr, const int* __restrict__ row_start,
    const float* __restrict__ We, const float* __restrict__ att,
    float* __restrict__ pm, float* __restrict__ pl, float* __restrict__ pacc,
    int* __restrict__ ctr,
    const float* __restrict__ gb, const float* __restrict__ lng,
    const float* __restrict__ lnb,
    const float* __restrict__ h_in,
    const float* __restrict__ x, const float* __restrict__ embW,
    const float* __restrict__ embb,
    float* __restrict__ h_out) {
  int nb = blockIdx.x;
  int n = nb >> 2, sgm = nb & (SEG - 1);
  int t = threadIdx.x;
  int g = t >> 5, l = t & 31, hd = l >> 2, qd = l & 3;
  int cb = hd*32 + qd*8;

  float xrv[8], w0[8], w1[8], w2[8], av[8];
#pragma unroll
  for (int j = 0; j < 8; ++j) {
    xrv[j] = xr[(size_t)n*HDIM + cb + j];
    w0[j]  = We[cb + j];
    w1[j]  = We[HDIM + cb + j];
    w2[j]  = We[2*HDIM + cb + j];
    av[j]  = att[cb + j];
  }
  int rs = row_start[n], re = row_start[n+1], len = re - rs;
  int s0 = rs + ((len * sgm) >> 2);
  int s1 = rs + ((len * (sgm + 1)) >> 2);

  float mh = -INFINITY, lh = 0.f;
  float acc[8] = {0.f,0.f,0.f,0.f,0.f,0.f,0.f,0.f};

  int idx = s0 + g;
  if (idx < s1) {
    float4 rec = csr[idx];
    while (idx < s1) {
      int idxn = idx + 8;
      float4 recn = csr[idxn < s1 ? idxn : rs];   // prefetch (rs always valid)
      int s = __float_as_int(rec.w);
      union { f16x8 v8; _Float16 h[8]; } ux;
      ux.v8 = *(const f16x8*)(xlh + (size_t)s*HDIM + cb);
      float xv[8];
#pragma unroll
      for (int j = 0; j < 8; ++j) xv[j] = (float)ux.h[j];
      float partial = 0.f;
#pragma unroll
      for (int j = 0; j < 8; ++j) {
        float m = fmaf(rec.z, w2[j], fmaf(rec.y, w1[j], fmaf(rec.x, w0[j], xrv[j]))) + xv[j];
        m = fmaxf(m, NEG * m);           // leaky_relu
        partial = fmaf(m, av[j], partial);
      }
      partial += __shfl_xor(partial, 1);
      partial += __shfl_xor(partial, 2); // all 4 lanes of head hold alpha
      if (partial > mh) {                // online softmax rescale
        float sc = __expf(mh - partial);
        lh *= sc;
#pragma unroll
        for (int j = 0; j < 8; ++j) acc[j] *= sc;
        mh = partial;
      }
      float pw = __expf(partial - mh);
      lh += pw;
#pragma unroll
      for (int j = 0; j < 8; ++j) acc[j] = fmaf(pw, xv[j], acc[j]);
      rec = recn; idx = idxn;
    }
  }

  __shared__ float lacc[8][HDIM];
  __shared__ float lm[8][NHEADS];
  __shared__ float llv[8][NHEADS];
#pragma unroll
  for (int j = 0; j < 8; ++j) lacc[g][cb + j] = acc[j];
  if (qd == 0) { lm[g][hd] = mh; llv[g][hd] = lh; }
  __syncthreads();

  // merge 8 group-partials; thread t owns channel c=t
  int c = t, hh = c >> 5;
  float M = -INFINITY;
#pragma unroll
  for (int g2 = 0; g2 < 8; ++g2) M = fmaxf(M, lm[g2][hh]);
  float L = 0.f, o = 0.f;
#pragma unroll
  for (int g2 = 0; g2 < 8; ++g2) {
    float e2 = __expf(lm[g2][hh] - M);
    L = fmaf(llv[g2][hh], e2, L);
    o = fmaf(lacc[g2][c], e2, o);
  }
  // publish partials (agent-scope, cross-XCD coherent)
  __hip_atomic_store(&pacc[(size_t)nb*HDIM + c], o, __ATOMIC_RELAXED, AGENT);
  if ((c & 31) == 0) {
    __hip_atomic_store(&pm[nb*NHEADS + hh], M, __ATOMIC_RELAXED, AGENT);
    __hip_atomic_store(&pl[nb*NHEADS + hh], L, __ATOMIC_RELAXED, AGENT);
  }
  __threadfence();
  __syncthreads();
  __shared__ int lastf;
  if (t == 0) {
    int old = __hip_atomic_fetch_add(&ctr[n], 1, __ATOMIC_ACQ_REL, AGENT);
    lastf = (old == SEG - 1);
  }
  __syncthreads();
  if (!lastf) return;
  __threadfence();

  // ---- last block for node n: merge SEG partials + residual + LayerNorm ----
  float M2 = -INFINITY, ms[SEG];
#pragma unroll
  for (int s = 0; s < SEG; ++s) {
    ms[s] = __hip_atomic_load(&pm[(n*SEG + s)*NHEADS + hh], __ATOMIC_RELAXED, AGENT);
    M2 = fmaxf(M2, ms[s]);
  }
  float L2 = 0.f, o2 = 0.f;
#pragma unroll
  for (int s = 0; s < SEG; ++s) {
    float e2 = __expf(ms[s] - M2);
    float ls = __hip_atomic_load(&pl[(n*SEG + s)*NHEADS + hh], __ATOMIC_RELAXED, AGENT);
    float os = __hip_atomic_load(&pacc[(size_t)(n*SEG + s)*HDIM + c], __ATOMIC_RELAXED, AGENT);
    L2 = fmaf(ls, e2, L2);
    o2 = fmaf(os, e2, o2);
  }
  float hi = h_in ? h_in[(size_t)n*HDIM + c] : fmaf(x[n], embW[c], embb[c]);
  float val = o2 / L2 + gb[c] + hi;

  float s1v = val, s2v = val * val;
#pragma unroll
  for (int off = 1; off < 64; off <<= 1) {
    s1v += __shfl_xor(s1v, off);
    s2v += __shfl_xor(s2v, off);
  }
  __shared__ float rs1[4], rs2[4];
  if ((t & 63) == 0) { rs1[t >> 6] = s1v; rs2[t >> 6] = s2v; }
  __syncthreads();
  float S1 = rs1[0] + rs1[1] + rs1[2] + rs1[3];
  float S2 = rs2[0] + rs2[1] + rs2[2] + rs2[3];
  float mu = S1 * (1.f/HDIM);
  float var = S2 * (1.f/HDIM) - mu * mu;
  float y = (val - mu) * rsqrtf(var + 1e-5f);
  y = fmaf(y, lng[c], lnb[c]);
  h_out[(size_t)n*HDIM + c] = fmaxf(y, 0.f);
}

// ---------------- all-pairs policy MLP via MFMA (register-direct, no LDS) ----
__global__ __launch_bounds__(256, 4) void pair_mfma_kernel(
    const float* __restrict__ A, const float* __restrict__ Bm,
    const unsigned short* __restrict__ W2h,
    const float* __restrict__ b2, const float* __restrict__ W3,
    const float* __restrict__ b3, float* __restrict__ out, int N) {
  // triangular tile decode: tiles (ti, tj), tj >= ti, 32x32 tiles of 16
  int bb = blockIdx.x;
  int half = bb & 1;
  int b = bb >> 1, ti = 0, rem = 32;
  while (b >= rem) { b -= rem; ti++; rem--; }
  int tj = ti + b;
  int i0 = ti * 16 + half * 8;     // block's 8 i-rows
  int j0 = tj * 16;

  int t = threadIdx.x;
  int w = t >> 6, l = t & 63;
  int quad = l >> 4, nl = l & 15;

  float b2v[8], w3v[8];
#pragma unroll
  for (int nt = 0; nt < 8; ++nt) {
    b2v[nt] = b2[nt*16 + nl];
    w3v[nt] = W3[nt*16 + nl];
  }

  const float* Brow = Bm + (size_t)(j0 + nl) * HDIM;   // lane's B row
  const float* Arow0 = A + (size_t)(i0 + w*2) * HDIM;  // wave's first A row

  f32x4 acc[2][8];
#pragma unroll
  for (int a2 = 0; a2 < 2; ++a2)
#pragma unroll
    for (int nt = 0; nt < 8; ++nt) acc[a2][nt] = (f32x4){0.f,0.f,0.f,0.f};

  for (int c = 0; c < 8; ++c) {       // K chunks of 32; lane covers 8 k's
    int kb = c*32 + quad*8;
    float4 bv0 = *(const float4*)(Brow + kb);
    float4 bv1 = *(const float4*)(Brow + kb + 4);

    f16x8 afrag[2];
#pragma unroll
    for (int a2 = 0; a2 < 2; ++a2) {
      const float* Ar = Arow0 + (size_t)a2*HDIM + kb;
      float4 av0 = *(const float4*)Ar;
      float4 av1 = *(const float4*)(Ar + 4);
      union { f16x8 v8; fp16v2 v2[4]; } u;
      u.v2[0] = __builtin_amdgcn_cvt_pkrtz(fmaxf(av0.x + bv0.x, 0.f),
                                           fmaxf(av0.y + bv0.y, 0.f));
      u.v2[1] = __builtin_amdgcn_cvt_pkrtz(fmaxf(av0.z + bv0.z, 0.f),
                                           fmaxf(av0.w + bv0.w, 0.f));
      u.v2[2] = __builtin_amdgcn_cvt_pkrtz(fmaxf(av1.x + bv1.x, 0.f),
                                           fmaxf(av1.y + bv1.y, 0.f));
      u.v2[3] = __builtin_amdgcn_cvt_pkrtz(fmaxf(av1.z + bv1.z, 0.f),
                                           fmaxf(av1.w + bv1.w, 0.f));
      afrag[a2] = u.v8;
    }

#pragma unroll
    for (int nt = 0; nt < 8; ++nt) {
      f16x8 bfrag = *(const f16x8*)(W2h + (size_t)(((c*8 + nt)*64 + l) * 8));
#pragma unroll
      for (int a2 = 0; a2 < 2; ++a2)
        acc[a2][nt] = __builtin_amdgcn_mfma_f32_16x16x32_f16(
            afrag[a2], bfrag, acc[a2][nt], 0, 0, 0);
    }
  }

  float b3v = b3[0];
#pragma unroll
  for (int a2 = 0; a2 < 2; ++a2) {
    int i = i0 + w*2 + a2;
#pragma unroll
    for (int r = 0; r < 4; ++r) {
      float s = 0.f;
#pragma unroll
      for (int nt = 0; nt < 8; ++nt)
        s = fmaf(fmaxf(acc[a2][nt][r] + b2v[nt], 0.f), w3v[nt], s);
      s += __shfl_xor(s, 1);
      s += __shfl_xor(s, 2);
      s += __shfl_xor(s, 4);
      s += __shfl_xor(s, 8);
      if (nl == 0) {
        int j = j0 + quad*4 + r;
        if (i < j)
          out[(size_t)i*(2*N - i - 1)/2 + (j - i - 1)] = s + b3v;
      }
    }
  }
}

// ---------------- value head: fused pool + matvec + last-block finish --------
__global__ __launch_bounds__(256) void value_fused(
    const float* __restrict__ h, const float* __restrict__ v1W,
    const float* __restrict__ v1b, const float* __restrict__ v2W,
    const float* __restrict__ v2b, float* __restrict__ vpart,
    int* __restrict__ vctr, float* __restrict__ out, int N) {
  int b = blockIdx.x, t = threadIdx.x;
  int k0 = b * 16;
  int kk = t >> 4, g = t & 15;
  __shared__ float repr16[16];
  int k = k0 + kk;
  float v;
  if (k < HDIM) {
    v = 0.f;
    for (int r = g; r < N; r += 16) v += h[(size_t)r*HDIM + k];
    v += __shfl_xor(v, 1); v += __shfl_xor(v, 2);
    v += __shfl_xor(v, 4); v += __shfl_xor(v, 8);
    if (g == 0) repr16[kk] = v / (float)N;
  } else {
    int kc = k - HDIM;
    v = -INFINITY;
    for (int r = g; r < N; r += 16) v = fmaxf(v, h[(size_t)r*HDIM + kc]);
    v = fmaxf(v, __shfl_xor(v, 1)); v = fmaxf(v, __shfl_xor(v, 2));
    v = fmaxf(v, __shfl_xor(v, 4)); v = fmaxf(v, __shfl_xor(v, 8));
    if (g == 0) repr16[kk] = v;
  }
  __syncthreads();
  float pv = 0.f;
#pragma unroll
  for (int q = 0; q < 16; ++q)
    pv = fmaf(repr16[q], v1W[(size_t)(k0 + q)*HDIM + t], pv);
  __hip_atomic_store(&vpart[b*HDIM + t], pv, __ATOMIC_RELAXED, AGENT);
  __threadfence();
  __syncthreads();
  __shared__ int lastf;
  if (t == 0) {
    int old = __hip_atomic_fetch_add(vctr, 1, __ATOMIC_ACQ_REL, AGENT);
    lastf = (old == 31);
  }
  __syncthreads();
  if (!lastf) return;
  __threadfence();
  float a = 0.f;
#pragma unroll
  for (int gg = 0; gg < 32; ++gg)
    a += __hip_atomic_load(&vpart[gg*HDIM + t], __ATOMIC_RELAXED, AGENT);
  a = fmaxf(a + v1b[t], 0.f);
  float fv = a * v2W[t];
#pragma unroll
  for (int off = 1; off < 64; off <<= 1) fv += __shfl_xor(fv, off);
  __shared__ float wsum[4];
  if ((t & 63) == 0) wsum[t >> 6] = fv;
  __syncthreads();
  if (t == 0) out[0] = wsum[0] + wsum[1] + wsum[2] + wsum[3] + v2b[0];
}

// ---------------- host orchestration ----------------
extern "C" void kernel_launch(void* const* d_in, const int* in_sizes, int n_in,
                              void* d_out, int out_size, void* d_ws, size_t ws_size,
                              hipStream_t stream) {
  const float* x    = (const float*)d_in[0];
  const int*   ei   = (const int*)  d_in[1];
  const float* ea   = (const float*)d_in[2];
  const float* embW = (const float*)d_in[3];
  const float* embb = (const float*)d_in[4];
  const float* Wl   = (const float*)d_in[5];
  const float* bl   = (const float*)d_in[6];
  const float* Wr   = (const float*)d_in[7];
  const float* br   = (const float*)d_in[8];
  const float* We   = (const float*)d_in[9];
  const float* att  = (const float*)d_in[10];
  const float* gb   = (const float*)d_in[11];
  const float* lng  = (const float*)d_in[12];
  const float* lnb  = (const float*)d_in[13];
  const float* p1W  = (const float*)d_in[14];
  const float* p1b  = (const float*)d_in[15];
  const float* p2W  = (const float*)d_in[16];
  const float* p2b  = (const float*)d_in[17];
  const float* p3W  = (const float*)d_in[18];
  const float* p3b  = (const float*)d_in[19];
  const float* v1W  = (const float*)d_in[20];
  const float* v1b  = (const float*)d_in[21];
  const float* v2W  = (const float*)d_in[22];
  const float* v2b  = (const float*)d_in[23];
  const float* coup = (const float*)d_in[24];

  int N = in_sizes[0];         // 512
  int E = in_sizes[2] / 3;     // 260000
  float* out = (float*)d_out;
  size_t P = (size_t)N*(N-1)/2;

  // ---- workspace carve (long-lived region first) ----
  char* w = (char*)d_ws;
  int*    rowp = (int*)   (w + 0);        // 2052 -> pad 2560
  float*  vprt = (float*) (w + 2560);     // 32768 -> 35328
  int*    ctr  = (int*)   (w + 35328);    // 4*512*4 = 8192 -> 43520
  int*    vctr = (int*)   (w + 43520);    // 4 -> pad 43776
  float4* csr  = (float4*)(w + 43776);    // (E+N)*16
  size_t csr_end = 43776 + (size_t)(E + N) * 16;
  csr_end = (csr_end + 255) & ~(size_t)255;
  float* hA  = (float*)(w + csr_end);
  float* hB  = hA  + (size_t)N*HDIM;
  float* xlb = hB  + (size_t)N*HDIM;
  float* xrb = xlb + (size_t)N*HDIM;
  float* Ab  = xrb + (size_t)N*HDIM;
  float* Bb  = Ab  + (size_t)N*HDIM;
  unsigned short* xlh   = (unsigned short*)(Bb + (size_t)N*HDIM); // N*256 f16
  unsigned short* W2h   = xlh + (size_t)N*HDIM;                   // 32768 f16
  unsigned short* Whall = W2h + 32768;                            // 10*65536 f16
  size_t ubase = ((size_t)((char*)(Whall + 10*65536) - w) + 255) & ~(size_t)255;

  // ---- union region: CSR-build scratch (phase 1) / attn partials (phase 2) --
  char* U = w + ubase;
  int*    pcnt = (int*)   (U + 0);        // NB*512*4          = 524288
  float*  psum = (float*) (U + 524288);   // 3*NB*512*4        = 1572864 -> 2097152
  int*    pcol = (int*)   (U + 2097152);  // 2*NB*512*4        = 1048576 -> 3145728
  int*    pbase= (int*)   (U + 3145728);  // NB*512*4          = 524288  -> 3670016
  int*    cnt  = (int*)   (U + 3670016);  // 2048
  float*  sred = (float*) (U + 3672064);  // 6144
  int*    dred = (int*)   (U + 3678208);  // 4096
  // phase 2 overlay (CSR scratch dead after scatter2):
  float*  pmv  = (float*) (U + 0);        // N*SEG*8*4   = 65536
  float*  plv  = (float*) (U + 65536);    // 65536
  float*  pacc = (float*) (U + 131072);   // N*SEG*256*4 = 2097152

  int CH = (E + NB - 1) / NB;
  edge_part<<<NB, 256, 0, stream>>>(ei, ea, E, CH, pcnt, psum, pcol);
  red_kernel<<<12, 256, 0, stream>>>(pcnt, psum, pcol, cnt, sred, dred, pbase);
  scan2<<<1, 512, 0, stream>>>(cnt, sred, dred, N, rowp, csr, coup, out + P + 1);
  scatter2<<<NB, 256, 0, stream>>>(ei, ea, E, CH, rowp, pbase, csr);
  w_prep_all<<<2688, 256, 0, stream>>>(Wl, Wr, p1W, p2W, Whall, W2h, ctr, vctr);

  float* hin = nullptr;        // layer 0: h computed on the fly from x
  float* hout = hB;
  for (int l = 0; l < 4; ++l) {
    dual_gemm_mfma<<<dim3(8, 32), 256, 0, stream>>>(hin, x, embW, embb,
        Whall + (size_t)l*65536, Whall + (size_t)(4 + l)*65536,
        bl + l*HDIM, br + l*HDIM, xlb, xrb, xlh);
    attn_fused<<<N*SEG, 256, 0, stream>>>(xlh, xrb, csr, rowp,
        We + (size_t)l*3*HDIM, att + (size_t)l*HDIM, pmv, plv, pacc,
        ctr + l*512,
        gb + (size_t)l*HDIM, lng + (size_t)l*HDIM, lnb + (size_t)l*HDIM,
        hin, x, embW, embb, hout);
    hin = hout;
    hout = (hout == hB) ? hA : hB;
  }
  // after 4 layers: hin = hA (final h)

  // pairs head: A = h@p1W[:256]+b1, B = h@p1W[256:]
  dual_gemm_mfma<<<dim3(8, 32), 256, 0, stream>>>(hin, x, embW, embb,
      Whall + (size_t)8*65536, Whall + (size_t)9*65536,
      p1b, (const float*)nullptr, Ab, Bb, (unsigned short*)nullptr);

  pair_mfma_kernel<<<1056, 256, 0, stream>>>(Ab, Bb, W2h, p2b, p3W, p3b, out, N);

  value_fused<<<32, 256, 0, stream>>>(hin, v1W, v1b, v2W, v2b,
                                      vprt, vctr, out + P, N);
}

// Round 13
// 322.353 us; speedup vs baseline: 3.8432x; 3.8432x over previous
//
#include <hip/hip_runtime.h>
#include <math.h>

#define HDIM 256
#define NHEADS 8
#define NEG 0.2f
#define NB 256  // edge-partition blocks for CSR build
#define NG 32   // edge groups per attention block (1024 threads)

typedef float f32x4 __attribute__((ext_vector_type(4)));
typedef _Float16 f16x8 __attribute__((ext_vector_type(8)));
typedef __fp16 fp16v2 __attribute__((ext_vector_type(2)));

// ---------------- CSR build, phase A: per-block LDS-privatized histograms ----
__global__ __launch_bounds__(256) void edge_part(
    const int* __restrict__ ei, const float* __restrict__ ea, int E, int CH,
    int* __restrict__ pcnt, float* __restrict__ psum, int* __restrict__ pcol) {
  __shared__ int   lcnt[512];
  __shared__ float ls0[512], ls1[512], ls2[512];
  __shared__ int   lcol[1024];
  int t = threadIdx.x, b = blockIdx.x;
  for (int n = t; n < 512; n += 256) {
    lcnt[n] = 0; ls0[n] = 0.f; ls1[n] = 0.f; ls2[n] = 0.f;
    lcol[n] = 0; lcol[512 + n] = 0;
  }
  __syncthreads();
  int e0 = b * CH, e1 = min(E, e0 + CH);
  for (int e = e0 + t; e < e1; e += 256) {
    int src = ei[e], dst = ei[E + e];
    float a0 = ea[3*e], a1 = ea[3*e+1], a2 = ea[3*e+2];
    atomicAdd(&lcnt[dst], 1);
    atomicAdd(&ls0[dst], a0);
    atomicAdd(&ls1[dst], a1);
    atomicAdd(&ls2[dst], a2);
    int idx = 0; float best = a0;
    if (a1 > best) { best = a1; idx = 1; }
    if (a2 > best) { idx = 2; }
    if (idx) {
      int o = (idx - 1) << 9;   // 0 or 512
      atomicAdd(&lcol[o + src], 1);
      atomicAdd(&lcol[o + dst], 1);
    }
  }
  __syncthreads();
  for (int n = t; n < 512; n += 256) {
    pcnt[b*512 + n] = lcnt[n];
    psum[(size_t)(0*NB + b)*512 + n] = ls0[n];
    psum[(size_t)(1*NB + b)*512 + n] = ls1[n];
    psum[(size_t)(2*NB + b)*512 + n] = ls2[n];
    pcol[(size_t)(0*NB + b)*512 + n] = lcol[n];
    pcol[(size_t)(1*NB + b)*512 + n] = lcol[512 + n];
  }
}

// ---------------- CSR build, phase B1: parallel partial reduction ------------
__global__ __launch_bounds__(256) void red_kernel(
    const int* __restrict__ pcnt, const float* __restrict__ psum,
    const int* __restrict__ pcol,
    int* __restrict__ cnt, float* __restrict__ sred, int* __restrict__ dred,
    int* __restrict__ pbase) {
  int q = blockIdx.x >> 1;
  int n = (blockIdx.x & 1)*256 + threadIdx.x;
  if (q == 0) {
    int run = 0;
#pragma unroll 8
    for (int b = 0; b < NB; ++b) {
      int v = pcnt[b*512 + n];
      pbase[b*512 + n] = run;
      run += v;
    }
    cnt[n] = run;
  } else if (q <= 3) {
    int qq = q - 1;
    float s = 0.f;
#pragma unroll 8
    for (int b = 0; b < NB; ++b) s += psum[(size_t)(qq*NB + b)*512 + n];
    sred[qq*512 + n] = s;
  } else {
    int qq = q - 4;
    int s = 0;
#pragma unroll 8
    for (int b = 0; b < NB; ++b) s += pcol[(size_t)(qq*NB + b)*512 + n];
    dred[qq*512 + n] = s;
  }
}

// ---------------- CSR build, phase B2: scan + self-loops + energy ------------
__global__ __launch_bounds__(512) void scan2(
    const int* __restrict__ cnt, const float* __restrict__ sred,
    const int* __restrict__ dred, int N,
    int* __restrict__ rowp, float4* __restrict__ csr,
    const float* __restrict__ coupling, float* __restrict__ eout) {
  int t = threadIdx.x;
  int c = (t < N) ? cnt[t] : 0;
  __shared__ int sbuf[512];
  int v = (t < N) ? (c + 1) : 0;    // +1 self-loop slot
  sbuf[t] = v;
  __syncthreads();
  for (int off = 1; off < 512; off <<= 1) {
    int add = (t >= off) ? sbuf[t - off] : 0;
    __syncthreads();
    sbuf[t] += add;
    __syncthreads();
  }
  int incl = sbuf[t], excl = incl - v;
  if (t < N) {
    rowp[t] = excl;
    if (t == N - 1) rowp[N] = incl;
    float inv = 1.f / fmaxf((float)c, 1.f);
    csr[excl] = make_float4(sred[t]*inv, sred[512 + t]*inv, sred[1024 + t]*inv,
                            __int_as_float(t));
  }
  // Potts energy from color-degree counts
  float e = 0.f;
  if (t < N) {
    float d1 = (float)dred[t], d2 = (float)dred[512 + t];
    e = d1*d1 + d2*d2;
  }
#pragma unroll
  for (int off = 1; off < 64; off <<= 1) e += __shfl_xor(e, off);
  __shared__ float wred[8];
  if ((t & 63) == 0) wred[t >> 6] = e;
  __syncthreads();
  if (t == 0) {
    float s = 0.f;
#pragma unroll
    for (int i = 0; i < 8; ++i) s += wred[i];
    eout[0] = coupling[0] * s / (2.f * (float)N);
  }
}

// ---------------- CSR build, phase C: scatter via LDS slot counters ----------
__global__ __launch_bounds__(256) void scatter2(
    const int* __restrict__ ei, const float* __restrict__ ea, int E, int CH,
    const int* __restrict__ rowp, const int* __restrict__ pbase,
    float4* __restrict__ csr) {
  __shared__ int lofs[512];
  int t = threadIdx.x, b = blockIdx.x;
  for (int n = t; n < 512; n += 256) lofs[n] = 0;
  __syncthreads();
  int e0 = b * CH, e1 = min(E, e0 + CH);
  for (int e = e0 + t; e < e1; e += 256) {
    int src = ei[e], dst = ei[E + e];
    float a0 = ea[3*e], a1 = ea[3*e+1], a2 = ea[3*e+2];
    int lp = atomicAdd(&lofs[dst], 1);
    int pos = rowp[dst] + 1 + pbase[b*512 + dst] + lp;
    csr[pos] = make_float4(a0, a1, a2, __int_as_float(src));
  }
}

// ---------------- weight prep: 10x[256x256] -> f16 B-frag + W2[256x128] -----
__global__ __launch_bounds__(256) void w_prep_all(
    const float* __restrict__ Wl, const float* __restrict__ Wr,
    const float* __restrict__ p1W, const float* __restrict__ W2,
    unsigned short* __restrict__ dst, unsigned short* __restrict__ W2h) {
  int gid = blockIdx.x * 256 + threadIdx.x;   // 10*65536 + 32768
  if (gid < 10*65536) {
    int s = gid >> 16, e = gid & 65535;
    int k = e >> 8, n = e & 255;
    const float* src = (s < 4) ? (Wl + (size_t)s*65536)
                     : (s < 8) ? (Wr + (size_t)(s-4)*65536)
                               : (p1W + (size_t)(s-8)*65536);
    int c = k >> 5, quad = (k >> 3) & 3, kj = k & 7;
    int nt = n >> 4, nl = n & 15;
    int lane = quad*16 + nl;
    _Float16 hv = (_Float16)src[(size_t)k*256 + n];
    dst[(size_t)s*65536 + ((nt*8 + c)*512 + lane*8 + kj)] = *(unsigned short*)&hv;
  } else {
    int e = gid - 10*65536;                   // 32768 W2 elems (pair head)
    int k = e >> 7, n = e & 127;
    int c = k >> 5, kq = (k >> 3) & 3, kj = k & 7;
    int nt = n >> 4, nl = n & 15;
    int lane = kq*16 + nl;
    _Float16 hv = (_Float16)W2[(size_t)k*128 + n];
    W2h[(size_t)(((c*8 + nt)*64 + lane)*8 + kj)] = *(unsigned short*)&hv;
  }
}

// ---------------- dual GEMM via MFMA: o1 = h@W1+b1, o2 = h@W2+b2 -------------
// Hm==nullptr -> h computed on the fly as x*embW+embb (layer 0).
__global__ __launch_bounds__(256) void dual_gemm_mfma(
    const float* __restrict__ Hm,
    const float* __restrict__ x, const float* __restrict__ embW,
    const float* __restrict__ embb,
    const unsigned short* __restrict__ W1h, const unsigned short* __restrict__ W2h,
    const float* __restrict__ b1, const float* __restrict__ b2,
    float* __restrict__ o1, float* __restrict__ o2,
    unsigned short* __restrict__ o1h) {
  int bx = blockIdx.x, by = blockIdx.y;
  int t = threadIdx.x, w = t >> 6, l = t & 63;
  int quad = l >> 4, nl = l & 15;
  int mt = bx*4 + w;

  const unsigned short* Wh; const float* bias; float* o; int nt;
  bool first = (by < 16);
  if (first) { Wh = W1h; bias = b1; o = o1; nt = by; }
  else       { Wh = W2h; bias = b2; o = o2; nt = by - 16; }

  int row = mt*16 + nl;
  const float* Ar = Hm ? (Hm + (size_t)row*HDIM + quad*8) : nullptr;
  float xm = Hm ? 0.f : x[row];
  f32x4 acc = (f32x4){0.f, 0.f, 0.f, 0.f};

#pragma unroll
  for (int c = 0; c < 8; ++c) {
    float4 a0, a1;
    if (Hm) {
      a0 = *(const float4*)(Ar + c*32);
      a1 = *(const float4*)(Ar + c*32 + 4);
    } else {
      int kb = c*32 + quad*8;
      float4 e0 = *(const float4*)(embW + kb);
      float4 e1 = *(const float4*)(embW + kb + 4);
      float4 c0 = *(const float4*)(embb + kb);
      float4 c1 = *(const float4*)(embb + kb + 4);
      a0 = make_float4(fmaf(xm, e0.x, c0.x), fmaf(xm, e0.y, c0.y),
                       fmaf(xm, e0.z, c0.z), fmaf(xm, e0.w, c0.w));
      a1 = make_float4(fmaf(xm, e1.x, c1.x), fmaf(xm, e1.y, c1.y),
                       fmaf(xm, e1.z, c1.z), fmaf(xm, e1.w, c1.w));
    }
    union { f16x8 v8; fp16v2 v2[4]; } u;
    u.v2[0] = __builtin_amdgcn_cvt_pkrtz(a0.x, a0.y);
    u.v2[1] = __builtin_amdgcn_cvt_pkrtz(a0.z, a0.w);
    u.v2[2] = __builtin_amdgcn_cvt_pkrtz(a1.x, a1.y);
    u.v2[3] = __builtin_amdgcn_cvt_pkrtz(a1.z, a1.w);
    f16x8 bfrag = *(const f16x8*)(Wh + (size_t)((nt*8 + c)*512 + l*8));
    acc = __builtin_amdgcn_mfma_f32_16x16x32_f16(u.v8, bfrag, acc, 0, 0, 0);
  }

  int colg = nt*16 + nl;
  float bv = bias ? bias[colg] : 0.f;
#pragma unroll
  for (int r = 0; r < 4; ++r) {
    float val = acc[r] + bv;
    size_t idx = (size_t)(mt*16 + quad*4 + r)*HDIM + colg;
    o[idx] = val;
    if (first && o1h) {
      _Float16 hv = (_Float16)val;
      o1h[idx] = *(unsigned short*)&hv;
    }
  }
}

// ---------------- GATv2 attention: one block per node (1024 thr, in-block) ---
// 32 groups of 32 lanes walk the edge list; LDS merge; residual + LayerNorm.
// No cross-block sync — the merge that cost 4 extra dispatches (R11) or
// device-scope fences (R12, 4x slower) is a single __syncthreads here.
__global__ __launch_bounds__(1024) void attn_one(
    const unsigned short* __restrict__ xlh, const float* __restrict__ xr,
    const float4* __restrict__ csr, const int* __restrict__ rowp,
    const float* __restrict__ We, const float* __restrict__ att,
    const float* __restrict__ gb, const float* __restrict__ lng,
    const float* __restrict__ lnb,
    const float* __restrict__ h_in,
    const float* __restrict__ x, const float* __restrict__ embW,
    const float* __restrict__ embb,
    float* __restrict__ h_out) {
  int n = blockIdx.x;
  int t = threadIdx.x;
  int g = t >> 5, l = t & 31, hd = l >> 2, qd = l & 3;
  int cb = hd*32 + qd*8;

  float xrv[8], w0[8], w1[8], w2[8], av[8];
#pragma unroll
  for (int j = 0; j < 8; ++j) {
    xrv[j] = xr[(size_t)n*HDIM + cb + j];
    w0[j]  = We[cb + j];
    w1[j]  = We[HDIM + cb + j];
    w2[j]  = We[2*HDIM + cb + j];
    av[j]  = att[cb + j];
  }
  int rs = rowp[n], re = rowp[n+1];

  float mh = -INFINITY, lh = 0.f;
  float acc[8] = {0.f,0.f,0.f,0.f,0.f,0.f,0.f,0.f};

  int idx = rs + g;
  if (idx < re) {
    float4 rec = csr[idx];
    while (idx < re) {
      int idxn = idx + NG;
      float4 recn = csr[idxn < re ? idxn : rs];   // prefetch (rs always valid)
      int s = __float_as_int(rec.w);
      union { f16x8 v8; _Float16 h[8]; } ux;
      ux.v8 = *(const f16x8*)(xlh + (size_t)s*HDIM + cb);
      float xv[8];
#pragma unroll
      for (int j = 0; j < 8; ++j) xv[j] = (float)ux.h[j];
      float partial = 0.f;
#pragma unroll
      for (int j = 0; j < 8; ++j) {
        float m = fmaf(rec.z, w2[j], fmaf(rec.y, w1[j], fmaf(rec.x, w0[j], xrv[j]))) + xv[j];
        m = fmaxf(m, NEG * m);           // leaky_relu
        partial = fmaf(m, av[j], partial);
      }
      partial += __shfl_xor(partial, 1);
      partial += __shfl_xor(partial, 2); // all 4 lanes of head hold alpha
      if (partial > mh) {                // online softmax rescale
        float sc = __expf(mh - partial);
        lh *= sc;
#pragma unroll
        for (int j = 0; j < 8; ++j) acc[j] *= sc;
        mh = partial;
      }
      float pw = __expf(partial - mh);
      lh += pw;
#pragma unroll
      for (int j = 0; j < 8; ++j) acc[j] = fmaf(pw, xv[j], acc[j]);
      rec = recn; idx = idxn;
    }
  }

  __shared__ float lacc[NG][HDIM];   // 32 KB
  __shared__ float lm[NG][NHEADS];
  __shared__ float llv[NG][NHEADS];
#pragma unroll
  for (int j = 0; j < 8; ++j) lacc[g][cb + j] = acc[j];
  if (qd == 0) { lm[g][hd] = mh; llv[g][hd] = lh; }
  __syncthreads();

  // threads 0..255 merge the 32 group-partials; channel c = t
  __shared__ float rsum1[4], rsum2[4];
  float val = 0.f;
  if (t < HDIM) {
    int c = t, hh = c >> 5;
    float M = -INFINITY;
#pragma unroll
    for (int g2 = 0; g2 < NG; ++g2) M = fmaxf(M, lm[g2][hh]);
    float L = 0.f, o = 0.f;
#pragma unroll
    for (int g2 = 0; g2 < NG; ++g2) {
      float e2 = __expf(lm[g2][hh] - M);
      L = fmaf(llv[g2][hh], e2, L);
      o = fmaf(lacc[g2][c], e2, o);
    }
    float hi = h_in ? h_in[(size_t)n*HDIM + c] : fmaf(x[n], embW[c], embb[c]);
    val = o / L + gb[c] + hi;
    float s1v = val, s2v = val * val;
#pragma unroll
    for (int off = 1; off < 64; off <<= 1) {
      s1v += __shfl_xor(s1v, off);
      s2v += __shfl_xor(s2v, off);
    }
    if ((t & 63) == 0) { rsum1[t >> 6] = s1v; rsum2[t >> 6] = s2v; }
  }
  __syncthreads();
  if (t < HDIM) {
    float S1 = rsum1[0] + rsum1[1] + rsum1[2] + rsum1[3];
    float S2 = rsum2[0] + rsum2[1] + rsum2[2] + rsum2[3];
    float mu = S1 * (1.f/HDIM);
    float var = S2 * (1.f/HDIM) - mu * mu;
    float y = (val - mu) * rsqrtf(var + 1e-5f);
    y = fmaf(y, lng[t], lnb[t]);
    h_out[(size_t)n*HDIM + t] = fmaxf(y, 0.f);
  }
}

// ---------------- all-pairs policy MLP via MFMA (register-direct, no LDS) ----
__global__ __launch_bounds__(256, 4) void pair_mfma_kernel(
    const float* __restrict__ A, const float* __restrict__ Bm,
    const unsigned short* __restrict__ W2h,
    const float* __restrict__ b2, const float* __restrict__ W3,
    const float* __restrict__ b3, float* __restrict__ out, int N) {
  // triangular tile decode: tiles (ti, tj), tj >= ti, 32x32 tiles of 16
  int bb = blockIdx.x;
  int half = bb & 1;
  int b = bb >> 1, ti = 0, rem = 32;
  while (b >= rem) { b -= rem; ti++; rem--; }
  int tj = ti + b;
  int i0 = ti * 16 + half * 8;     // block's 8 i-rows
  int j0 = tj * 16;

  int t = threadIdx.x;
  int w = t >> 6, l = t & 63;
  int quad = l >> 4, nl = l & 15;

  float b2v[8], w3v[8];
#pragma unroll
  for (int nt = 0; nt < 8; ++nt) {
    b2v[nt] = b2[nt*16 + nl];
    w3v[nt] = W3[nt*16 + nl];
  }

  const float* Brow = Bm + (size_t)(j0 + nl) * HDIM;   // lane's B row
  const float* Arow0 = A + (size_t)(i0 + w*2) * HDIM;  // wave's first A row

  f32x4 acc[2][8];
#pragma unroll
  for (int a2 = 0; a2 < 2; ++a2)
#pragma unroll
    for (int nt = 0; nt < 8; ++nt) acc[a2][nt] = (f32x4){0.f,0.f,0.f,0.f};

  for (int c = 0; c < 8; ++c) {       // K chunks of 32; lane covers 8 k's
    int kb = c*32 + quad*8;
    float4 bv0 = *(const float4*)(Brow + kb);
    float4 bv1 = *(const float4*)(Brow + kb + 4);

    f16x8 afrag[2];
#pragma unroll
    for (int a2 = 0; a2 < 2; ++a2) {
      const float* Ar = Arow0 + (size_t)a2*HDIM + kb;
      float4 av0 = *(const float4*)Ar;
      float4 av1 = *(const float4*)(Ar + 4);
      union { f16x8 v8; fp16v2 v2[4]; } u;
      u.v2[0] = __builtin_amdgcn_cvt_pkrtz(fmaxf(av0.x + bv0.x, 0.f),
                                           fmaxf(av0.y + bv0.y, 0.f));
      u.v2[1] = __builtin_amdgcn_cvt_pkrtz(fmaxf(av0.z + bv0.z, 0.f),
                                           fmaxf(av0.w + bv0.w, 0.f));
      u.v2[2] = __builtin_amdgcn_cvt_pkrtz(fmaxf(av1.x + bv1.x, 0.f),
                                           fmaxf(av1.y + bv1.y, 0.f));
      u.v2[3] = __builtin_amdgcn_cvt_pkrtz(fmaxf(av1.z + bv1.z, 0.f),
                                           fmaxf(av1.w + bv1.w, 0.f));
      afrag[a2] = u.v8;
    }

#pragma unroll
    for (int nt = 0; nt < 8; ++nt) {
      f16x8 bfrag = *(const f16x8*)(W2h + (size_t)(((c*8 + nt)*64 + l) * 8));
#pragma unroll
      for (int a2 = 0; a2 < 2; ++a2)
        acc[a2][nt] = __builtin_amdgcn_mfma_f32_16x16x32_f16(
            afrag[a2], bfrag, acc[a2][nt], 0, 0, 0);
    }
  }

  float b3v = b3[0];
#pragma unroll
  for (int a2 = 0; a2 < 2; ++a2) {
    int i = i0 + w*2 + a2;
#pragma unroll
    for (int r = 0; r < 4; ++r) {
      float s = 0.f;
#pragma unroll
      for (int nt = 0; nt < 8; ++nt)
        s = fmaf(fmaxf(acc[a2][nt][r] + b2v[nt], 0.f), w3v[nt], s);
      s += __shfl_xor(s, 1);
      s += __shfl_xor(s, 2);
      s += __shfl_xor(s, 4);
      s += __shfl_xor(s, 8);
      if (nl == 0) {
        int j = j0 + quad*4 + r;
        if (i < j)
          out[(size_t)i*(2*N - i - 1)/2 + (j - i - 1)] = s + b3v;
      }
    }
  }
}

// ---------------- value head, stage 1: pooling partials (32 blocks) ----------
__global__ __launch_bounds__(256) void pool_kernel(
    const float* __restrict__ h, float* __restrict__ psums,
    float* __restrict__ pmaxs) {
  int g = blockIdx.x, t = threadIdx.x;
  float s = 0.f, m = -INFINITY;
#pragma unroll
  for (int r = 0; r < 16; ++r) {
    float v = h[(size_t)(g*16 + r)*HDIM + t];
    s += v; m = fmaxf(m, v);
  }
  psums[g*HDIM + t] = s;
  pmaxs[g*HDIM + t] = m;
}

// ---------------- value head, stage 2: partial matvec (32 blocks) ------------
__global__ __launch_bounds__(256) void value1_kernel(
    const float* __restrict__ psums, const float* __restrict__ pmaxs,
    const float* __restrict__ v1W, float* __restrict__ vpart, int N) {
  int b = blockIdx.x, t = threadIdx.x;
  int k0 = b * 16;
  int kk = t >> 4, g = t & 15;
  __shared__ float repr16[16];
  int k = k0 + kk;
  float v;
  if (k < HDIM) {
    v = psums[g*HDIM + k] + psums[(g + 16)*HDIM + k];
    v += __shfl_xor(v, 1); v += __shfl_xor(v, 2);
    v += __shfl_xor(v, 4); v += __shfl_xor(v, 8);
    if (g == 0) repr16[kk] = v / (float)N;
  } else {
    int kc = k - HDIM;
    v = fmaxf(pmaxs[g*HDIM + kc], pmaxs[(g + 16)*HDIM + kc]);
    v = fmaxf(v, __shfl_xor(v, 1)); v = fmaxf(v, __shfl_xor(v, 2));
    v = fmaxf(v, __shfl_xor(v, 4)); v = fmaxf(v, __shfl_xor(v, 8));
    if (g == 0) repr16[kk] = v;
  }
  __syncthreads();
  float pv = 0.f;
#pragma unroll
  for (int q = 0; q < 16; ++q)
    pv = fmaf(repr16[q], v1W[(size_t)(k0 + q)*HDIM + t], pv);
  vpart[b*HDIM + t] = pv;
}

// ---------------- value head, stage 3: finish (1 block) ----------------------
__global__ __launch_bounds__(256) void value2_kernel(
    const float* __restrict__ vpart, const float* __restrict__ v1b,
    const float* __restrict__ v2W, const float* __restrict__ v2b,
    float* __restrict__ out) {
  int t = threadIdx.x;
  float a = 0.f;
#pragma unroll
  for (int g = 0; g < 32; ++g) a += vpart[g*HDIM + t];
  a = fmaxf(a + v1b[t], 0.f);
  float pv = a * v2W[t];
#pragma unroll
  for (int off = 1; off < 64; off <<= 1) pv += __shfl_xor(pv, off);
  __shared__ float wsum[4];
  if ((t & 63) == 0) wsum[t >> 6] = pv;
  __syncthreads();
  if (t == 0) out[0] = wsum[0] + wsum[1] + wsum[2] + wsum[3] + v2b[0];
}

// ---------------- host orchestration ----------------
extern "C" void kernel_launch(void* const* d_in, const int* in_sizes, int n_in,
                              void* d_out, int out_size, void* d_ws, size_t ws_size,
                              hipStream_t stream) {
  const float* x    = (const float*)d_in[0];
  const int*   ei   = (const int*)  d_in[1];
  const float* ea   = (const float*)d_in[2];
  const float* embW = (const float*)d_in[3];
  const float* embb = (const float*)d_in[4];
  const float* Wl   = (const float*)d_in[5];
  const float* bl   = (const float*)d_in[6];
  const float* Wr   = (const float*)d_in[7];
  const float* br   = (const float*)d_in[8];
  const float* We   = (const float*)d_in[9];
  const float* att  = (const float*)d_in[10];
  const float* gb   = (const float*)d_in[11];
  const float* lng  = (const float*)d_in[12];
  const float* lnb  = (const float*)d_in[13];
  const float* p1W  = (const float*)d_in[14];
  const float* p1b  = (const float*)d_in[15];
  const float* p2W  = (const float*)d_in[16];
  const float* p2b  = (const float*)d_in[17];
  const float* p3W  = (const float*)d_in[18];
  const float* p3b  = (const float*)d_in[19];
  const float* v1W  = (const float*)d_in[20];
  const float* v1b  = (const float*)d_in[21];
  const float* v2W  = (const float*)d_in[22];
  const float* v2b  = (const float*)d_in[23];
  const float* coup = (const float*)d_in[24];

  int N = in_sizes[0];         // 512
  int E = in_sizes[2] / 3;     // 260000
  float* out = (float*)d_out;
  size_t P = (size_t)N*(N-1)/2;

  // ---- workspace carve (long-lived region first) ----
  char* w = (char*)d_ws;
  int*    rowp = (int*)   (w + 0);        // 2052 -> pad 2560
  float*  plS  = (float*) (w + 2560);     // 32768 -> 35328
  float*  plM  = (float*) (w + 35328);    // 32768 -> 68096
  float*  vprt = (float*) (w + 68096);    // 32768 -> 100864 -> pad 101120
  float4* csr  = (float4*)(w + 101120);   // (E+N)*16
  size_t csr_end = 101120 + (size_t)(E + N) * 16;
  csr_end = (csr_end + 255) & ~(size_t)255;
  float* hA  = (float*)(w + csr_end);
  float* hB  = hA  + (size_t)N*HDIM;
  float* xlb = hB  + (size_t)N*HDIM;
  float* xrb = xlb + (size_t)N*HDIM;
  float* Ab  = xrb + (size_t)N*HDIM;
  float* Bb  = Ab  + (size_t)N*HDIM;
  unsigned short* xlh   = (unsigned short*)(Bb + (size_t)N*HDIM); // N*256 f16
  unsigned short* W2h   = xlh + (size_t)N*HDIM;                   // 32768 f16
  unsigned short* Whall = W2h + 32768;                            // 10*65536 f16
  size_t ubase = ((size_t)((char*)(Whall + 10*65536) - w) + 255) & ~(size_t)255;

  // ---- union region: CSR-build scratch (dead after scatter2) ----
  char* U = w + ubase;
  int*    pcnt = (int*)   (U + 0);        // NB*512*4          = 524288
  float*  psum = (float*) (U + 524288);   // 3*NB*512*4        = 1572864 -> 2097152
  int*    pcol = (int*)   (U + 2097152);  // 2*NB*512*4        = 1048576 -> 3145728
  int*    pbase= (int*)   (U + 3145728);  // NB*512*4          = 524288  -> 3670016
  int*    cnt  = (int*)   (U + 3670016);  // 2048
  float*  sred = (float*) (U + 3672064);  // 6144
  int*    dred = (int*)   (U + 3678208);  // 4096

  int CH = (E + NB - 1) / NB;
  edge_part<<<NB, 256, 0, stream>>>(ei, ea, E, CH, pcnt, psum, pcol);
  red_kernel<<<12, 256, 0, stream>>>(pcnt, psum, pcol, cnt, sred, dred, pbase);
  scan2<<<1, 512, 0, stream>>>(cnt, sred, dred, N, rowp, csr, coup, out + P + 1);
  scatter2<<<NB, 256, 0, stream>>>(ei, ea, E, CH, rowp, pbase, csr);
  w_prep_all<<<2688, 256, 0, stream>>>(Wl, Wr, p1W, p2W, Whall, W2h);

  float* hin = nullptr;        // layer 0: h computed on the fly from x
  float* hout = hB;
  for (int l = 0; l < 4; ++l) {
    dual_gemm_mfma<<<dim3(8, 32), 256, 0, stream>>>(hin, x, embW, embb,
        Whall + (size_t)l*65536, Whall + (size_t)(4 + l)*65536,
        bl + l*HDIM, br + l*HDIM, xlb, xrb, xlh);
    attn_one<<<N, 1024, 0, stream>>>(xlh, xrb, csr, rowp,
        We + (size_t)l*3*HDIM, att + (size_t)l*HDIM,
        gb + (size_t)l*HDIM, lng + (size_t)l*HDIM, lnb + (size_t)l*HDIM,
        hin, x, embW, embb, hout);
    hin = hout;
    hout = (hout == hB) ? hA : hB;
  }
  // after 4 layers: hin points at final h

  // pairs head: A = h@p1W[:256]+b1, B = h@p1W[256:]
  dual_gemm_mfma<<<dim3(8, 32), 256, 0, stream>>>(hin, x, embW, embb,
      Whall + (size_t)8*65536, Whall + (size_t)9*65536,
      p1b, (const float*)nullptr, Ab, Bb, (unsigned short*)nullptr);

  pair_mfma_kernel<<<1056, 256, 0, stream>>>(Ab, Bb, W2h, p2b, p3W, p3b, out, N);

  pool_kernel<<<32, 256, 0, stream>>>(hin, plS, plM);
  value1_kernel<<<32, 256, 0, stream>>>(plS, plM, v1W, vprt, N);
  value2_kernel<<<1, 256, 0, stream>>>(vprt, v1b, v2W, v2b, out + P);
}

// Round 14
// 309.943 us; speedup vs baseline: 3.9970x; 1.0400x over previous
//
#include <hip/hip_runtime.h>
#include <math.h>

#define HDIM 256
#define NHEADS 8
#define NEG 0.2f
#define NB 256  // edge-partition blocks for CSR build
#define SEG 4   // attention edge-list segments per node

typedef float f32x4 __attribute__((ext_vector_type(4)));
typedef _Float16 f16x8 __attribute__((ext_vector_type(8)));
typedef __fp16 fp16v2 __attribute__((ext_vector_type(2)));

// ---------------- CSR build, phase A: per-block LDS-privatized histograms ----
__global__ __launch_bounds__(256) void edge_part(
    const int* __restrict__ ei, const float* __restrict__ ea, int E, int CH,
    int* __restrict__ pcnt, float* __restrict__ psum, int* __restrict__ pcol) {
  __shared__ int   lcnt[512];
  __shared__ float ls0[512], ls1[512], ls2[512];
  __shared__ int   lcol[1024];
  int t = threadIdx.x, b = blockIdx.x;
  for (int n = t; n < 512; n += 256) {
    lcnt[n] = 0; ls0[n] = 0.f; ls1[n] = 0.f; ls2[n] = 0.f;
    lcol[n] = 0; lcol[512 + n] = 0;
  }
  __syncthreads();
  int e0 = b * CH, e1 = min(E, e0 + CH);
  for (int e = e0 + t; e < e1; e += 256) {
    int src = ei[e], dst = ei[E + e];
    float a0 = ea[3*e], a1 = ea[3*e+1], a2 = ea[3*e+2];
    atomicAdd(&lcnt[dst], 1);
    atomicAdd(&ls0[dst], a0);
    atomicAdd(&ls1[dst], a1);
    atomicAdd(&ls2[dst], a2);
    int idx = 0; float best = a0;
    if (a1 > best) { best = a1; idx = 1; }
    if (a2 > best) { idx = 2; }
    if (idx) {
      int o = (idx - 1) << 9;   // 0 or 512
      atomicAdd(&lcol[o + src], 1);
      atomicAdd(&lcol[o + dst], 1);
    }
  }
  __syncthreads();
  for (int n = t; n < 512; n += 256) {
    pcnt[b*512 + n] = lcnt[n];
    psum[(size_t)(0*NB + b)*512 + n] = ls0[n];
    psum[(size_t)(1*NB + b)*512 + n] = ls1[n];
    psum[(size_t)(2*NB + b)*512 + n] = ls2[n];
    pcol[(size_t)(0*NB + b)*512 + n] = lcol[n];
    pcol[(size_t)(1*NB + b)*512 + n] = lcol[512 + n];
  }
}

// ---------------- CSR build, phase B1: parallel partial reduction ------------
__global__ __launch_bounds__(256) void red_kernel(
    const int* __restrict__ pcnt, const float* __restrict__ psum,
    const int* __restrict__ pcol,
    int* __restrict__ cnt, float* __restrict__ sred, int* __restrict__ dred,
    int* __restrict__ pbase) {
  int q = blockIdx.x >> 1;
  int n = (blockIdx.x & 1)*256 + threadIdx.x;
  if (q == 0) {
    int run = 0;
#pragma unroll 8
    for (int b = 0; b < NB; ++b) {
      int v = pcnt[b*512 + n];
      pbase[b*512 + n] = run;
      run += v;
    }
    cnt[n] = run;
  } else if (q <= 3) {
    int qq = q - 1;
    float s = 0.f;
#pragma unroll 8
    for (int b = 0; b < NB; ++b) s += psum[(size_t)(qq*NB + b)*512 + n];
    sred[qq*512 + n] = s;
  } else {
    int qq = q - 4;
    int s = 0;
#pragma unroll 8
    for (int b = 0; b < NB; ++b) s += pcol[(size_t)(qq*NB + b)*512 + n];
    dred[qq*512 + n] = s;
  }
}

// ---------------- CSR build, phase B2: scan + self-loops + energy ------------
__global__ __launch_bounds__(512) void scan2(
    const int* __restrict__ cnt, const float* __restrict__ sred,
    const int* __restrict__ dred, int N,
    int* __restrict__ rowp, float4* __restrict__ csr,
    const float* __restrict__ coupling, float* __restrict__ eout) {
  int t = threadIdx.x;
  int c = (t < N) ? cnt[t] : 0;
  __shared__ int sbuf[512];
  int v = (t < N) ? (c + 1) : 0;    // +1 self-loop slot
  sbuf[t] = v;
  __syncthreads();
  for (int off = 1; off < 512; off <<= 1) {
    int add = (t >= off) ? sbuf[t - off] : 0;
    __syncthreads();
    sbuf[t] += add;
    __syncthreads();
  }
  int incl = sbuf[t], excl = incl - v;
  if (t < N) {
    rowp[t] = excl;
    if (t == N - 1) rowp[N] = incl;
    float inv = 1.f / fmaxf((float)c, 1.f);
    csr[excl] = make_float4(sred[t]*inv, sred[512 + t]*inv, sred[1024 + t]*inv,
                            __int_as_float(t));
  }
  // Potts energy from color-degree counts
  float e = 0.f;
  if (t < N) {
    float d1 = (float)dred[t], d2 = (float)dred[512 + t];
    e = d1*d1 + d2*d2;
  }
#pragma unroll
  for (int off = 1; off < 64; off <<= 1) e += __shfl_xor(e, off);
  __shared__ float wred[8];
  if ((t & 63) == 0) wred[t >> 6] = e;
  __syncthreads();
  if (t == 0) {
    float s = 0.f;
#pragma unroll
    for (int i = 0; i < 8; ++i) s += wred[i];
    eout[0] = coupling[0] * s / (2.f * (float)N);
  }
}

// ---------------- CSR build, phase C: scatter via LDS slot counters ----------
__global__ __launch_bounds__(256) void scatter2(
    const int* __restrict__ ei, const float* __restrict__ ea, int E, int CH,
    const int* __restrict__ rowp, const int* __restrict__ pbase,
    float4* __restrict__ csr) {
  __shared__ int lofs[512];
  int t = threadIdx.x, b = blockIdx.x;
  for (int n = t; n < 512; n += 256) lofs[n] = 0;
  __syncthreads();
  int e0 = b * CH, e1 = min(E, e0 + CH);
  for (int e = e0 + t; e < e1; e += 256) {
    int src = ei[e], dst = ei[E + e];
    float a0 = ea[3*e], a1 = ea[3*e+1], a2 = ea[3*e+2];
    int lp = atomicAdd(&lofs[dst], 1);
    int pos = rowp[dst] + 1 + pbase[b*512 + dst] + lp;
    csr[pos] = make_float4(a0, a1, a2, __int_as_float(src));
  }
}

// ---------------- weight prep: 10x[256x256] -> f16 B-frag + W2[256x128] -----
__global__ __launch_bounds__(256) void w_prep_all(
    const float* __restrict__ Wl, const float* __restrict__ Wr,
    const float* __restrict__ p1W, const float* __restrict__ W2,
    unsigned short* __restrict__ dst, unsigned short* __restrict__ W2h) {
  int gid = blockIdx.x * 256 + threadIdx.x;   // 10*65536 + 32768
  if (gid < 10*65536) {
    int s = gid >> 16, e = gid & 65535;
    int k = e >> 8, n = e & 255;
    const float* src = (s < 4) ? (Wl + (size_t)s*65536)
                     : (s < 8) ? (Wr + (size_t)(s-4)*65536)
                               : (p1W + (size_t)(s-8)*65536);
    int c = k >> 5, quad = (k >> 3) & 3, kj = k & 7;
    int nt = n >> 4, nl = n & 15;
    int lane = quad*16 + nl;
    _Float16 hv = (_Float16)src[(size_t)k*256 + n];
    dst[(size_t)s*65536 + ((nt*8 + c)*512 + lane*8 + kj)] = *(unsigned short*)&hv;
  } else {
    int e = gid - 10*65536;                   // 32768 W2 elems (pair head)
    int k = e >> 7, n = e & 127;
    int c = k >> 5, kq = (k >> 3) & 3, kj = k & 7;
    int nt = n >> 4, nl = n & 15;
    int lane = kq*16 + nl;
    _Float16 hv = (_Float16)W2[(size_t)k*128 + n];
    W2h[(size_t)(((c*8 + nt)*64 + lane)*8 + kj)] = *(unsigned short*)&hv;
  }
}

// ---------------- dual GEMM via MFMA: o1 = h@W1+b1, o2 = h@W2+b2 -------------
// Hm==nullptr -> h computed on the fly as x*embW+embb (layer 0).
__global__ __launch_bounds__(256) void dual_gemm_mfma(
    const float* __restrict__ Hm,
    const float* __restrict__ x, const float* __restrict__ embW,
    const float* __restrict__ embb,
    const unsigned short* __restrict__ W1h, const unsigned short* __restrict__ W2h,
    const float* __restrict__ b1, const float* __restrict__ b2,
    float* __restrict__ o1, float* __restrict__ o2,
    unsigned short* __restrict__ o1h) {
  int bx = blockIdx.x, by = blockIdx.y;
  int t = threadIdx.x, w = t >> 6, l = t & 63;
  int quad = l >> 4, nl = l & 15;
  int mt = bx*4 + w;

  const unsigned short* Wh; const float* bias; float* o; int nt;
  bool first = (by < 16);
  if (first) { Wh = W1h; bias = b1; o = o1; nt = by; }
  else       { Wh = W2h; bias = b2; o = o2; nt = by - 16; }

  int row = mt*16 + nl;
  const float* Ar = Hm ? (Hm + (size_t)row*HDIM + quad*8) : nullptr;
  float xm = Hm ? 0.f : x[row];
  f32x4 acc = (f32x4){0.f, 0.f, 0.f, 0.f};

#pragma unroll
  for (int c = 0; c < 8; ++c) {
    float4 a0, a1;
    if (Hm) {
      a0 = *(const float4*)(Ar + c*32);
      a1 = *(const float4*)(Ar + c*32 + 4);
    } else {
      int kb = c*32 + quad*8;
      float4 e0 = *(const float4*)(embW + kb);
      float4 e1 = *(const float4*)(embW + kb + 4);
      float4 c0 = *(const float4*)(embb + kb);
      float4 c1 = *(const float4*)(embb + kb + 4);
      a0 = make_float4(fmaf(xm, e0.x, c0.x), fmaf(xm, e0.y, c0.y),
                       fmaf(xm, e0.z, c0.z), fmaf(xm, e0.w, c0.w));
      a1 = make_float4(fmaf(xm, e1.x, c1.x), fmaf(xm, e1.y, c1.y),
                       fmaf(xm, e1.z, c1.z), fmaf(xm, e1.w, c1.w));
    }
    union { f16x8 v8; fp16v2 v2[4]; } u;
    u.v2[0] = __builtin_amdgcn_cvt_pkrtz(a0.x, a0.y);
    u.v2[1] = __builtin_amdgcn_cvt_pkrtz(a0.z, a0.w);
    u.v2[2] = __builtin_amdgcn_cvt_pkrtz(a1.x, a1.y);
    u.v2[3] = __builtin_amdgcn_cvt_pkrtz(a1.z, a1.w);
    f16x8 bfrag = *(const f16x8*)(Wh + (size_t)((nt*8 + c)*512 + l*8));
    acc = __builtin_amdgcn_mfma_f32_16x16x32_f16(u.v8, bfrag, acc, 0, 0, 0);
  }

  int colg = nt*16 + nl;
  float bv = bias ? bias[colg] : 0.f;
#pragma unroll
  for (int r = 0; r < 4; ++r) {
    float val = acc[r] + bv;
    size_t idx = (size_t)(mt*16 + quad*4 + r)*HDIM + colg;
    o[idx] = val;
    if (first && o1h) {
      _Float16 hv = (_Float16)val;
      o1h[idx] = *(unsigned short*)&hv;
    }
  }
}

// ---------------- GATv2 attention, stage 1: segmented gather (2-deep SWP) ----
// grid N*SEG; rec prefetched 2 ahead, xlh gather prefetched 1 ahead, so the
// dependent-gather latency overlaps the previous edge's ~35-VALU compute.
__global__ __launch_bounds__(256) void attn_gather(
    const unsigned short* __restrict__ xlh, const float* __restrict__ xr,
    const float4* __restrict__ csr, const int* __restrict__ row_start,
    const float* __restrict__ We, const float* __restrict__ att,
    float* __restrict__ pm, float* __restrict__ pl, float* __restrict__ pacc) {
  int nb = blockIdx.x;
  int n = nb >> 2, sgm = nb & (SEG - 1);
  int t = threadIdx.x;
  int g = t >> 5, l = t & 31, hd = l >> 2, qd = l & 3;
  int cb = hd*32 + qd*8;

  float xrv[8], w0[8], w1[8], w2[8], av[8];
#pragma unroll
  for (int j = 0; j < 8; ++j) {
    xrv[j] = xr[(size_t)n*HDIM + cb + j];
    w0[j]  = We[cb + j];
    w1[j]  = We[HDIM + cb + j];
    w2[j]  = We[2*HDIM + cb + j];
    av[j]  = att[cb + j];
  }
  int rs = row_start[n], re = row_start[n+1], len = re - rs;
  int s0 = rs + ((len * sgm) >> 2);
  int s1 = rs + ((len * (sgm + 1)) >> 2);

  float mh = -INFINITY, lh = 0.f;
  float acc[8] = {0.f,0.f,0.f,0.f,0.f,0.f,0.f,0.f};

  int idx = s0 + g;
  if (idx < s1) {
    float4 rec = csr[idx];
    int idx1 = idx + 8;
    float4 rec1 = csr[idx1 < s1 ? idx1 : rs];
    union { f16x8 v8; _Float16 h[8]; } cur, nxt;
    cur.v8 = *(const f16x8*)(xlh + (size_t)__float_as_int(rec.w)*HDIM + cb);
    while (idx < s1) {
      int idx2 = idx1 + 8;
      float4 rec2 = csr[idx2 < s1 ? idx2 : rs];            // rec prefetch (2-deep)
      nxt.v8 = *(const f16x8*)(xlh +                       // gather prefetch (1-deep)
                (size_t)__float_as_int(rec1.w)*HDIM + cb);
      float xv[8];
#pragma unroll
      for (int j = 0; j < 8; ++j) xv[j] = (float)cur.h[j];
      float partial = 0.f;
#pragma unroll
      for (int j = 0; j < 8; ++j) {
        float m = fmaf(rec.z, w2[j], fmaf(rec.y, w1[j], fmaf(rec.x, w0[j], xrv[j]))) + xv[j];
        m = fmaxf(m, NEG * m);           // leaky_relu
        partial = fmaf(m, av[j], partial);
      }
      partial += __shfl_xor(partial, 1);
      partial += __shfl_xor(partial, 2); // all 4 lanes of head hold alpha
      if (partial > mh) {                // online softmax rescale
        float sc = __expf(mh - partial);
        lh *= sc;
#pragma unroll
        for (int j = 0; j < 8; ++j) acc[j] *= sc;
        mh = partial;
      }
      float pw = __expf(partial - mh);
      lh += pw;
#pragma unroll
      for (int j = 0; j < 8; ++j) acc[j] = fmaf(pw, xv[j], acc[j]);
      rec = rec1; rec1 = rec2; cur.v8 = nxt.v8;
      idx = idx1; idx1 = idx2;
    }
  }

  __shared__ float lacc[8][HDIM];
  __shared__ float lm[8][NHEADS];
  __shared__ float llv[8][NHEADS];
#pragma unroll
  for (int j = 0; j < 8; ++j) lacc[g][cb + j] = acc[j];
  if (qd == 0) { lm[g][hd] = mh; llv[g][hd] = lh; }
  __syncthreads();

  // merge 8 group-partials; thread t owns channel c=t
  int c = t, hh = c >> 5;
  float M = -INFINITY;
#pragma unroll
  for (int g2 = 0; g2 < 8; ++g2) M = fmaxf(M, lm[g2][hh]);
  float L = 0.f, o = 0.f;
#pragma unroll
  for (int g2 = 0; g2 < 8; ++g2) {
    float e2 = __expf(lm[g2][hh] - M);
    L = fmaf(llv[g2][hh], e2, L);
    o = fmaf(lacc[g2][c], e2, o);
  }
  pacc[(size_t)nb*HDIM + c] = o;
  if ((c & 31) == 0) {
    pm[nb*NHEADS + hh] = M;
    pl[nb*NHEADS + hh] = L;
  }
}

// ---------------- GATv2 attention, stage 2: merge + residual + LayerNorm -----
// h_in==nullptr -> residual computed on the fly as x*embW+embb (layer 0).
__global__ __launch_bounds__(256) void attn_merge(
    const float* __restrict__ pm, const float* __restrict__ pl,
    const float* __restrict__ pacc,
    const float* __restrict__ gb, const float* __restrict__ lng,
    const float* __restrict__ lnb,
    const float* __restrict__ h_in,
    const float* __restrict__ x, const float* __restrict__ embW,
    const float* __restrict__ embb,
    float* __restrict__ h_out) {
  int n = blockIdx.x, t = threadIdx.x;
  int c = t, hh = c >> 5;
  float M = -INFINITY;
#pragma unroll
  for (int s = 0; s < SEG; ++s) M = fmaxf(M, pm[(n*SEG + s)*NHEADS + hh]);
  float L = 0.f, o = 0.f;
#pragma unroll
  for (int s = 0; s < SEG; ++s) {
    float e2 = __expf(pm[(n*SEG + s)*NHEADS + hh] - M);
    L = fmaf(pl[(n*SEG + s)*NHEADS + hh], e2, L);
    o = fmaf(pacc[(size_t)(n*SEG + s)*HDIM + c], e2, o);
  }
  float hi = h_in ? h_in[(size_t)n*HDIM + c] : fmaf(x[n], embW[c], embb[c]);
  float val = o / L + gb[c] + hi;

  // LayerNorm over 256 channels + relu
  float s1 = val, s2 = val * val;
#pragma unroll
  for (int off = 1; off < 64; off <<= 1) {
    s1 += __shfl_xor(s1, off);
    s2 += __shfl_xor(s2, off);
  }
  __shared__ float rs1[4], rs2[4];
  if ((t & 63) == 0) { rs1[t >> 6] = s1; rs2[t >> 6] = s2; }
  __syncthreads();
  float S1 = rs1[0] + rs1[1] + rs1[2] + rs1[3];
  float S2 = rs2[0] + rs2[1] + rs2[2] + rs2[3];
  float mu = S1 * (1.f/HDIM);
  float var = S2 * (1.f/HDIM) - mu * mu;
  float y = (val - mu) * rsqrtf(var + 1e-5f);
  y = fmaf(y, lng[c], lnb[c]);
  h_out[(size_t)n*HDIM + c] = fmaxf(y, 0.f);
}

// ---------------- all-pairs policy MLP via MFMA (register-direct, no LDS) ----
__global__ __launch_bounds__(256, 4) void pair_mfma_kernel(
    const float* __restrict__ A, const float* __restrict__ Bm,
    const unsigned short* __restrict__ W2h,
    const float* __restrict__ b2, const float* __restrict__ W3,
    const float* __restrict__ b3, float* __restrict__ out, int N) {
  // triangular tile decode: tiles (ti, tj), tj >= ti, 32x32 tiles of 16
  int bb = blockIdx.x;
  int half = bb & 1;
  int b = bb >> 1, ti = 0, rem = 32;
  while (b >= rem) { b -= rem; ti++; rem--; }
  int tj = ti + b;
  int i0 = ti * 16 + half * 8;     // block's 8 i-rows
  int j0 = tj * 16;

  int t = threadIdx.x;
  int w = t >> 6, l = t & 63;
  int quad = l >> 4, nl = l & 15;

  float b2v[8], w3v[8];
#pragma unroll
  for (int nt = 0; nt < 8; ++nt) {
    b2v[nt] = b2[nt*16 + nl];
    w3v[nt] = W3[nt*16 + nl];
  }

  const float* Brow = Bm + (size_t)(j0 + nl) * HDIM;   // lane's B row
  const float* Arow0 = A + (size_t)(i0 + w*2) * HDIM;  // wave's first A row

  f32x4 acc[2][8];
#pragma unroll
  for (int a2 = 0; a2 < 2; ++a2)
#pragma unroll
    for (int nt = 0; nt < 8; ++nt) acc[a2][nt] = (f32x4){0.f,0.f,0.f,0.f};

  for (int c = 0; c < 8; ++c) {       // K chunks of 32; lane covers 8 k's
    int kb = c*32 + quad*8;
    float4 bv0 = *(const float4*)(Brow + kb);
    float4 bv1 = *(const float4*)(Brow + kb + 4);

    f16x8 afrag[2];
#pragma unroll
    for (int a2 = 0; a2 < 2; ++a2) {
      const float* Ar = Arow0 + (size_t)a2*HDIM + kb;
      float4 av0 = *(const float4*)Ar;
      float4 av1 = *(const float4*)(Ar + 4);
      union { f16x8 v8; fp16v2 v2[4]; } u;
      u.v2[0] = __builtin_amdgcn_cvt_pkrtz(fmaxf(av0.x + bv0.x, 0.f),
                                           fmaxf(av0.y + bv0.y, 0.f));
      u.v2[1] = __builtin_amdgcn_cvt_pkrtz(fmaxf(av0.z + bv0.z, 0.f),
                                           fmaxf(av0.w + bv0.w, 0.f));
      u.v2[2] = __builtin_amdgcn_cvt_pkrtz(fmaxf(av1.x + bv1.x, 0.f),
                                           fmaxf(av1.y + bv1.y, 0.f));
      u.v2[3] = __builtin_amdgcn_cvt_pkrtz(fmaxf(av1.z + bv1.z, 0.f),
                                           fmaxf(av1.w + bv1.w, 0.f));
      afrag[a2] = u.v8;
    }

#pragma unroll
    for (int nt = 0; nt < 8; ++nt) {
      f16x8 bfrag = *(const f16x8*)(W2h + (size_t)(((c*8 + nt)*64 + l) * 8));
#pragma unroll
      for (int a2 = 0; a2 < 2; ++a2)
        acc[a2][nt] = __builtin_amdgcn_mfma_f32_16x16x32_f16(
            afrag[a2], bfrag, acc[a2][nt], 0, 0, 0);
    }
  }

  float b3v = b3[0];
#pragma unroll
  for (int a2 = 0; a2 < 2; ++a2) {
    int i = i0 + w*2 + a2;
#pragma unroll
    for (int r = 0; r < 4; ++r) {
      float s = 0.f;
#pragma unroll
      for (int nt = 0; nt < 8; ++nt)
        s = fmaf(fmaxf(acc[a2][nt][r] + b2v[nt], 0.f), w3v[nt], s);
      s += __shfl_xor(s, 1);
      s += __shfl_xor(s, 2);
      s += __shfl_xor(s, 4);
      s += __shfl_xor(s, 8);
      if (nl == 0) {
        int j = j0 + quad*4 + r;
        if (i < j)
          out[(size_t)i*(2*N - i - 1)/2 + (j - i - 1)] = s + b3v;
      }
    }
  }
}

// ---------------- value head, stage 1: pooling partials (32 blocks) ----------
__global__ __launch_bounds__(256) void pool_kernel(
    const float* __restrict__ h, float* __restrict__ psums,
    float* __restrict__ pmaxs) {
  int g = blockIdx.x, t = threadIdx.x;
  float s = 0.f, m = -INFINITY;
#pragma unroll
  for (int r = 0; r < 16; ++r) {
    float v = h[(size_t)(g*16 + r)*HDIM + t];
    s += v; m = fmaxf(m, v);
  }
  psums[g*HDIM + t] = s;
  pmaxs[g*HDIM + t] = m;
}

// ---------------- value head, stage 2: partial matvec (32 blocks) ------------
__global__ __launch_bounds__(256) void value1_kernel(
    const float* __restrict__ psums, const float* __restrict__ pmaxs,
    const float* __restrict__ v1W, float* __restrict__ vpart, int N) {
  int b = blockIdx.x, t = threadIdx.x;
  int k0 = b * 16;
  int kk = t >> 4, g = t & 15;
  __shared__ float repr16[16];
  int k = k0 + kk;
  float v;
  if (k < HDIM) {
    v = psums[g*HDIM + k] + psums[(g + 16)*HDIM + k];
    v += __shfl_xor(v, 1); v += __shfl_xor(v, 2);
    v += __shfl_xor(v, 4); v += __shfl_xor(v, 8);
    if (g == 0) repr16[kk] = v / (float)N;
  } else {
    int kc = k - HDIM;
    v = fmaxf(pmaxs[g*HDIM + kc], pmaxs[(g + 16)*HDIM + kc]);
    v = fmaxf(v, __shfl_xor(v, 1)); v = fmaxf(v, __shfl_xor(v, 2));
    v = fmaxf(v, __shfl_xor(v, 4)); v = fmaxf(v, __shfl_xor(v, 8));
    if (g == 0) repr16[kk] = v;
  }
  __syncthreads();
  float pv = 0.f;
#pragma unroll
  for (int q = 0; q < 16; ++q)
    pv = fmaf(repr16[q], v1W[(size_t)(k0 + q)*HDIM + t], pv);
  vpart[b*HDIM + t] = pv;
}

// ---------------- value head, stage 3: finish (1 block) ----------------------
__global__ __launch_bounds__(256) void value2_kernel(
    const float* __restrict__ vpart, const float* __restrict__ v1b,
    const float* __restrict__ v2W, const float* __restrict__ v2b,
    float* __restrict__ out) {
  int t = threadIdx.x;
  float a = 0.f;
#pragma unroll
  for (int g = 0; g < 32; ++g) a += vpart[g*HDIM + t];
  a = fmaxf(a + v1b[t], 0.f);
  float pv = a * v2W[t];
#pragma unroll
  for (int off = 1; off < 64; off <<= 1) pv += __shfl_xor(pv, off);
  __shared__ float wsum[4];
  if ((t & 63) == 0) wsum[t >> 6] = pv;
  __syncthreads();
  if (t == 0) out[0] = wsum[0] + wsum[1] + wsum[2] + wsum[3] + v2b[0];
}

// ---------------- host orchestration ----------------
extern "C" void kernel_launch(void* const* d_in, const int* in_sizes, int n_in,
                              void* d_out, int out_size, void* d_ws, size_t ws_size,
                              hipStream_t stream) {
  const float* x    = (const float*)d_in[0];
  const int*   ei   = (const int*)  d_in[1];
  const float* ea   = (const float*)d_in[2];
  const float* embW = (const float*)d_in[3];
  const float* embb = (const float*)d_in[4];
  const float* Wl   = (const float*)d_in[5];
  const float* bl   = (const float*)d_in[6];
  const float* Wr   = (const float*)d_in[7];
  const float* br   = (const float*)d_in[8];
  const float* We   = (const float*)d_in[9];
  const float* att  = (const float*)d_in[10];
  const float* gb   = (const float*)d_in[11];
  const float* lng  = (const float*)d_in[12];
  const float* lnb  = (const float*)d_in[13];
  const float* p1W  = (const float*)d_in[14];
  const float* p1b  = (const float*)d_in[15];
  const float* p2W  = (const float*)d_in[16];
  const float* p2b  = (const float*)d_in[17];
  const float* p3W  = (const float*)d_in[18];
  const float* p3b  = (const float*)d_in[19];
  const float* v1W  = (const float*)d_in[20];
  const float* v1b  = (const float*)d_in[21];
  const float* v2W  = (const float*)d_in[22];
  const float* v2b  = (const float*)d_in[23];
  const float* coup = (const float*)d_in[24];

  int N = in_sizes[0];         // 512
  int E = in_sizes[2] / 3;     // 260000
  float* out = (float*)d_out;
  size_t P = (size_t)N*(N-1)/2;

  // ---- workspace carve (long-lived region first) ----
  char* w = (char*)d_ws;
  int*    rowp = (int*)   (w + 0);        // 2052 -> pad 2560
  float*  plS  = (float*) (w + 2560);     // 32768 -> 35328
  float*  plM  = (float*) (w + 35328);    // 32768 -> 68096
  float*  vprt = (float*) (w + 68096);    // 32768 -> 100864 -> pad 101120
  float4* csr  = (float4*)(w + 101120);   // (E+N)*16
  size_t csr_end = 101120 + (size_t)(E + N) * 16;
  csr_end = (csr_end + 255) & ~(size_t)255;
  float* hA  = (float*)(w + csr_end);
  float* hB  = hA  + (size_t)N*HDIM;
  float* xlb = hB  + (size_t)N*HDIM;
  float* xrb = xlb + (size_t)N*HDIM;
  float* Ab  = xrb + (size_t)N*HDIM;
  float* Bb  = Ab  + (size_t)N*HDIM;
  unsigned short* xlh   = (unsigned short*)(Bb + (size_t)N*HDIM); // N*256 f16
  unsigned short* W2h   = xlh + (size_t)N*HDIM;                   // 32768 f16
  unsigned short* Whall = W2h + 32768;                            // 10*65536 f16
  size_t ubase = ((size_t)((char*)(Whall + 10*65536) - w) + 255) & ~(size_t)255;

  // ---- union region: CSR-build scratch (phase 1) / attn partials (phase 2) --
  char* U = w + ubase;
  int*    pcnt = (int*)   (U + 0);        // NB*512*4          = 524288
  float*  psum = (float*) (U + 524288);   // 3*NB*512*4        = 1572864 -> 2097152
  int*    pcol = (int*)   (U + 2097152);  // 2*NB*512*4        = 1048576 -> 3145728
  int*    pbase= (int*)   (U + 3145728);  // NB*512*4          = 524288  -> 3670016
  int*    cnt  = (int*)   (U + 3670016);  // 2048
  float*  sred = (float*) (U + 3672064);  // 6144
  int*    dred = (int*)   (U + 3678208);  // 4096
  // phase 2 overlay (CSR scratch dead after scatter2):
  float*  pmv  = (float*) (U + 0);        // N*SEG*8*4   = 65536
  float*  plv  = (float*) (U + 65536);    // 65536
  float*  pacc = (float*) (U + 131072);   // N*SEG*256*4 = 2097152

  int CH = (E + NB - 1) / NB;
  edge_part<<<NB, 256, 0, stream>>>(ei, ea, E, CH, pcnt, psum, pcol);
  red_kernel<<<12, 256, 0, stream>>>(pcnt, psum, pcol, cnt, sred, dred, pbase);
  scan2<<<1, 512, 0, stream>>>(cnt, sred, dred, N, rowp, csr, coup, out + P + 1);
  scatter2<<<NB, 256, 0, stream>>>(ei, ea, E, CH, rowp, pbase, csr);
  w_prep_all<<<2688, 256, 0, stream>>>(Wl, Wr, p1W, p2W, Whall, W2h);

  float* hin = nullptr;        // layer 0: h computed on the fly from x
  float* hout = hB;
  for (int l = 0; l < 4; ++l) {
    dual_gemm_mfma<<<dim3(8, 32), 256, 0, stream>>>(hin, x, embW, embb,
        Whall + (size_t)l*65536, Whall + (size_t)(4 + l)*65536,
        bl + l*HDIM, br + l*HDIM, xlb, xrb, xlh);
    attn_gather<<<N*SEG, 256, 0, stream>>>(xlh, xrb, csr, rowp,
        We + (size_t)l*3*HDIM, att + (size_t)l*HDIM, pmv, plv, pacc);
    attn_merge<<<N, 256, 0, stream>>>(pmv, plv, pacc,
        gb + (size_t)l*HDIM, lng + (size_t)l*HDIM, lnb + (size_t)l*HDIM,
        hin, x, embW, embb, hout);
    hin = hout;
    hout = (hout == hB) ? hA : hB;
  }
  // after 4 layers: hin points at final h

  // pairs head: A = h@p1W[:256]+b1, B = h@p1W[256:]
  dual_gemm_mfma<<<dim3(8, 32), 256, 0, stream>>>(hin, x, embW, embb,
      Whall + (size_t)8*65536, Whall + (size_t)9*65536,
      p1b, (const float*)nullptr, Ab, Bb, (unsigned short*)nullptr);

  pair_mfma_kernel<<<1056, 256, 0, stream>>>(Ab, Bb, W2h, p2b, p3W, p3b, out, N);

  pool_kernel<<<32, 256, 0, stream>>>(hin, plS, plM);
  value1_kernel<<<32, 256, 0, stream>>>(plS, plM, v1W, vprt, N);
  value2_kernel<<<1, 256, 0, stream>>>(vprt, v1b, v2W, v2b, out + P);
}

// Round 15
// 306.460 us; speedup vs baseline: 4.0425x; 1.0114x over previous
//
#include <hip/hip_runtime.h>
#include <math.h>

#define HDIM 256
#define NHEADS 8
#define NEG 0.2f
#define NB 256  // edge-partition blocks for CSR build
#define SEG 4   // attention edge-list segments per node

typedef float f32x4 __attribute__((ext_vector_type(4)));
typedef _Float16 f16x8 __attribute__((ext_vector_type(8)));
typedef __fp16 fp16v2 __attribute__((ext_vector_type(2)));

// ---------------- CSR build, phase A: per-block LDS-privatized histograms ----
__global__ __launch_bounds__(256) void edge_part(
    const int* __restrict__ ei, const float* __restrict__ ea, int E, int CH,
    int* __restrict__ pcnt, float* __restrict__ psum, int* __restrict__ pcol) {
  __shared__ int   lcnt[512];
  __shared__ float ls0[512], ls1[512], ls2[512];
  __shared__ int   lcol[1024];
  int t = threadIdx.x, b = blockIdx.x;
  for (int n = t; n < 512; n += 256) {
    lcnt[n] = 0; ls0[n] = 0.f; ls1[n] = 0.f; ls2[n] = 0.f;
    lcol[n] = 0; lcol[512 + n] = 0;
  }
  __syncthreads();
  int e0 = b * CH, e1 = min(E, e0 + CH);
  for (int e = e0 + t; e < e1; e += 256) {
    int src = ei[e], dst = ei[E + e];
    float a0 = ea[3*e], a1 = ea[3*e+1], a2 = ea[3*e+2];
    atomicAdd(&lcnt[dst], 1);
    atomicAdd(&ls0[dst], a0);
    atomicAdd(&ls1[dst], a1);
    atomicAdd(&ls2[dst], a2);
    int idx = 0; float best = a0;
    if (a1 > best) { best = a1; idx = 1; }
    if (a2 > best) { idx = 2; }
    if (idx) {
      int o = (idx - 1) << 9;   // 0 or 512
      atomicAdd(&lcol[o + src], 1);
      atomicAdd(&lcol[o + dst], 1);
    }
  }
  __syncthreads();
  for (int n = t; n < 512; n += 256) {
    pcnt[b*512 + n] = lcnt[n];
    psum[(size_t)(0*NB + b)*512 + n] = ls0[n];
    psum[(size_t)(1*NB + b)*512 + n] = ls1[n];
    psum[(size_t)(2*NB + b)*512 + n] = ls2[n];
    pcol[(size_t)(0*NB + b)*512 + n] = lcol[n];
    pcol[(size_t)(1*NB + b)*512 + n] = lcol[512 + n];
  }
}

// ---------------- CSR build, phase B1: parallel partial reduction ------------
__global__ __launch_bounds__(256) void red_kernel(
    const int* __restrict__ pcnt, const float* __restrict__ psum,
    const int* __restrict__ pcol,
    int* __restrict__ cnt, float* __restrict__ sred, int* __restrict__ dred,
    int* __restrict__ pbase) {
  int q = blockIdx.x >> 1;
  int n = (blockIdx.x & 1)*256 + threadIdx.x;
  if (q == 0) {
    int run = 0;
#pragma unroll 8
    for (int b = 0; b < NB; ++b) {
      int v = pcnt[b*512 + n];
      pbase[b*512 + n] = run;
      run += v;
    }
    cnt[n] = run;
  } else if (q <= 3) {
    int qq = q - 1;
    float s = 0.f;
#pragma unroll 8
    for (int b = 0; b < NB; ++b) s += psum[(size_t)(qq*NB + b)*512 + n];
    sred[qq*512 + n] = s;
  } else {
    int qq = q - 4;
    int s = 0;
#pragma unroll 8
    for (int b = 0; b < NB; ++b) s += pcol[(size_t)(qq*NB + b)*512 + n];
    dred[qq*512 + n] = s;
  }
}

// ---------------- CSR build, phase B2: scan + self-loops + energy ------------
__global__ __launch_bounds__(512) void scan2(
    const int* __restrict__ cnt, const float* __restrict__ sred,
    const int* __restrict__ dred, int N,
    int* __restrict__ rowp, float4* __restrict__ csr,
    const float* __restrict__ coupling, float* __restrict__ eout) {
  int t = threadIdx.x;
  int c = (t < N) ? cnt[t] : 0;
  __shared__ int sbuf[512];
  int v = (t < N) ? (c + 1) : 0;    // +1 self-loop slot
  sbuf[t] = v;
  __syncthreads();
  for (int off = 1; off < 512; off <<= 1) {
    int add = (t >= off) ? sbuf[t - off] : 0;
    __syncthreads();
    sbuf[t] += add;
    __syncthreads();
  }
  int incl = sbuf[t], excl = incl - v;
  if (t < N) {
    rowp[t] = excl;
    if (t == N - 1) rowp[N] = incl;
    float inv = 1.f / fmaxf((float)c, 1.f);
    csr[excl] = make_float4(sred[t]*inv, sred[512 + t]*inv, sred[1024 + t]*inv,
                            __int_as_float(t));
  }
  // Potts energy from color-degree counts
  float e = 0.f;
  if (t < N) {
    float d1 = (float)dred[t], d2 = (float)dred[512 + t];
    e = d1*d1 + d2*d2;
  }
#pragma unroll
  for (int off = 1; off < 64; off <<= 1) e += __shfl_xor(e, off);
  __shared__ float wred[8];
  if ((t & 63) == 0) wred[t >> 6] = e;
  __syncthreads();
  if (t == 0) {
    float s = 0.f;
#pragma unroll
    for (int i = 0; i < 8; ++i) s += wred[i];
    eout[0] = coupling[0] * s / (2.f * (float)N);
  }
}

// ---------------- CSR build, phase C: scatter via LDS slot counters ----------
__global__ __launch_bounds__(256) void scatter2(
    const int* __restrict__ ei, const float* __restrict__ ea, int E, int CH,
    const int* __restrict__ rowp, const int* __restrict__ pbase,
    float4* __restrict__ csr) {
  __shared__ int lofs[512];
  int t = threadIdx.x, b = blockIdx.x;
  for (int n = t; n < 512; n += 256) lofs[n] = 0;
  __syncthreads();
  int e0 = b * CH, e1 = min(E, e0 + CH);
  for (int e = e0 + t; e < e1; e += 256) {
    int src = ei[e], dst = ei[E + e];
    float a0 = ea[3*e], a1 = ea[3*e+1], a2 = ea[3*e+2];
    int lp = atomicAdd(&lofs[dst], 1);
    int pos = rowp[dst] + 1 + pbase[b*512 + dst] + lp;
    csr[pos] = make_float4(a0, a1, a2, __int_as_float(src));
  }
}

// ---------------- weight prep: 10x[256x256] -> f16 B-frag + W2[256x128] -----
__global__ __launch_bounds__(256) void w_prep_all(
    const float* __restrict__ Wl, const float* __restrict__ Wr,
    const float* __restrict__ p1W, const float* __restrict__ W2,
    unsigned short* __restrict__ dst, unsigned short* __restrict__ W2h) {
  int gid = blockIdx.x * 256 + threadIdx.x;   // 10*65536 + 32768
  if (gid < 10*65536) {
    int s = gid >> 16, e = gid & 65535;
    int k = e >> 8, n = e & 255;
    const float* src = (s < 4) ? (Wl + (size_t)s*65536)
                     : (s < 8) ? (Wr + (size_t)(s-4)*65536)
                               : (p1W + (size_t)(s-8)*65536);
    int c = k >> 5, quad = (k >> 3) & 3, kj = k & 7;
    int nt = n >> 4, nl = n & 15;
    int lane = quad*16 + nl;
    _Float16 hv = (_Float16)src[(size_t)k*256 + n];
    dst[(size_t)s*65536 + ((nt*8 + c)*512 + lane*8 + kj)] = *(unsigned short*)&hv;
  } else {
    int e = gid - 10*65536;                   // 32768 W2 elems (pair head)
    int k = e >> 7, n = e & 127;
    int c = k >> 5, kq = (k >> 3) & 3, kj = k & 7;
    int nt = n >> 4, nl = n & 15;
    int lane = kq*16 + nl;
    _Float16 hv = (_Float16)W2[(size_t)k*128 + n];
    W2h[(size_t)(((c*8 + nt)*64 + lane)*8 + kj)] = *(unsigned short*)&hv;
  }
}

// ---------------- dual GEMM via MFMA: o = h@W+b; f32 and/or f16 outputs ------
// Hm==nullptr -> h computed on the fly as x*embW+embb (layer 0).
__global__ __launch_bounds__(256) void dual_gemm_mfma(
    const float* __restrict__ Hm,
    const float* __restrict__ x, const float* __restrict__ embW,
    const float* __restrict__ embb,
    const unsigned short* __restrict__ W1h, const unsigned short* __restrict__ W2h,
    const float* __restrict__ b1, const float* __restrict__ b2,
    float* __restrict__ o1, unsigned short* __restrict__ o1h,
    float* __restrict__ o2, unsigned short* __restrict__ o2h) {
  int bx = blockIdx.x, by = blockIdx.y;
  int t = threadIdx.x, w = t >> 6, l = t & 63;
  int quad = l >> 4, nl = l & 15;
  int mt = bx*4 + w;

  const unsigned short* Wh; const float* bias; float* o; unsigned short* oh; int nt;
  bool first = (by < 16);
  if (first) { Wh = W1h; bias = b1; o = o1; oh = o1h; nt = by; }
  else       { Wh = W2h; bias = b2; o = o2; oh = o2h; nt = by - 16; }

  int row = mt*16 + nl;
  const float* Ar = Hm ? (Hm + (size_t)row*HDIM + quad*8) : nullptr;
  float xm = Hm ? 0.f : x[row];
  f32x4 acc = (f32x4){0.f, 0.f, 0.f, 0.f};

#pragma unroll
  for (int c = 0; c < 8; ++c) {
    float4 a0, a1;
    if (Hm) {
      a0 = *(const float4*)(Ar + c*32);
      a1 = *(const float4*)(Ar + c*32 + 4);
    } else {
      int kb = c*32 + quad*8;
      float4 e0 = *(const float4*)(embW + kb);
      float4 e1 = *(const float4*)(embW + kb + 4);
      float4 c0 = *(const float4*)(embb + kb);
      float4 c1 = *(const float4*)(embb + kb + 4);
      a0 = make_float4(fmaf(xm, e0.x, c0.x), fmaf(xm, e0.y, c0.y),
                       fmaf(xm, e0.z, c0.z), fmaf(xm, e0.w, c0.w));
      a1 = make_float4(fmaf(xm, e1.x, c1.x), fmaf(xm, e1.y, c1.y),
                       fmaf(xm, e1.z, c1.z), fmaf(xm, e1.w, c1.w));
    }
    union { f16x8 v8; fp16v2 v2[4]; } u;
    u.v2[0] = __builtin_amdgcn_cvt_pkrtz(a0.x, a0.y);
    u.v2[1] = __builtin_amdgcn_cvt_pkrtz(a0.z, a0.w);
    u.v2[2] = __builtin_amdgcn_cvt_pkrtz(a1.x, a1.y);
    u.v2[3] = __builtin_amdgcn_cvt_pkrtz(a1.z, a1.w);
    f16x8 bfrag = *(const f16x8*)(Wh + (size_t)((nt*8 + c)*512 + l*8));
    acc = __builtin_amdgcn_mfma_f32_16x16x32_f16(u.v8, bfrag, acc, 0, 0, 0);
  }

  int colg = nt*16 + nl;
  float bv = bias ? bias[colg] : 0.f;
#pragma unroll
  for (int r = 0; r < 4; ++r) {
    float val = acc[r] + bv;
    size_t idx = (size_t)(mt*16 + quad*4 + r)*HDIM + colg;
    if (o) o[idx] = val;
    if (oh) {
      _Float16 hv = (_Float16)val;
      oh[idx] = *(unsigned short*)&hv;
    }
  }
}

// ---------------- GATv2 attention, stage 1: segmented gather (2-deep SWP) ----
__global__ __launch_bounds__(256) void attn_gather(
    const unsigned short* __restrict__ xlh, const float* __restrict__ xr,
    const float4* __restrict__ csr, const int* __restrict__ row_start,
    const float* __restrict__ We, const float* __restrict__ att,
    float* __restrict__ pm, float* __restrict__ pl, float* __restrict__ pacc) {
  int nb = blockIdx.x;
  int n = nb >> 2, sgm = nb & (SEG - 1);
  int t = threadIdx.x;
  int g = t >> 5, l = t & 31, hd = l >> 2, qd = l & 3;
  int cb = hd*32 + qd*8;

  float xrv[8], w0[8], w1[8], w2[8], av[8];
#pragma unroll
  for (int j = 0; j < 8; ++j) {
    xrv[j] = xr[(size_t)n*HDIM + cb + j];
    w0[j]  = We[cb + j];
    w1[j]  = We[HDIM + cb + j];
    w2[j]  = We[2*HDIM + cb + j];
    av[j]  = att[cb + j];
  }
  int rs = row_start[n], re = row_start[n+1], len = re - rs;
  int s0 = rs + ((len * sgm) >> 2);
  int s1 = rs + ((len * (sgm + 1)) >> 2);

  float mh = -INFINITY, lh = 0.f;
  float acc[8] = {0.f,0.f,0.f,0.f,0.f,0.f,0.f,0.f};

  int idx = s0 + g;
  if (idx < s1) {
    float4 rec = csr[idx];
    int idx1 = idx + 8;
    float4 rec1 = csr[idx1 < s1 ? idx1 : rs];
    union { f16x8 v8; _Float16 h[8]; } cur, nxt;
    cur.v8 = *(const f16x8*)(xlh + (size_t)__float_as_int(rec.w)*HDIM + cb);
    while (idx < s1) {
      int idx2 = idx1 + 8;
      float4 rec2 = csr[idx2 < s1 ? idx2 : rs];            // rec prefetch (2-deep)
      nxt.v8 = *(const f16x8*)(xlh +                       // gather prefetch (1-deep)
                (size_t)__float_as_int(rec1.w)*HDIM + cb);
      float xv[8];
#pragma unroll
      for (int j = 0; j < 8; ++j) xv[j] = (float)cur.h[j];
      float partial = 0.f;
#pragma unroll
      for (int j = 0; j < 8; ++j) {
        float m = fmaf(rec.z, w2[j], fmaf(rec.y, w1[j], fmaf(rec.x, w0[j], xrv[j]))) + xv[j];
        m = fmaxf(m, NEG * m);           // leaky_relu
        partial = fmaf(m, av[j], partial);
      }
      partial += __shfl_xor(partial, 1);
      partial += __shfl_xor(partial, 2); // all 4 lanes of head hold alpha
      if (partial > mh) {                // online softmax rescale
        float sc = __expf(mh - partial);
        lh *= sc;
#pragma unroll
        for (int j = 0; j < 8; ++j) acc[j] *= sc;
        mh = partial;
      }
      float pw = __expf(partial - mh);
      lh += pw;
#pragma unroll
      for (int j = 0; j < 8; ++j) acc[j] = fmaf(pw, xv[j], acc[j]);
      rec = rec1; rec1 = rec2; cur.v8 = nxt.v8;
      idx = idx1; idx1 = idx2;
    }
  }

  __shared__ float lacc[8][HDIM];
  __shared__ float lm[8][NHEADS];
  __shared__ float llv[8][NHEADS];
#pragma unroll
  for (int j = 0; j < 8; ++j) lacc[g][cb + j] = acc[j];
  if (qd == 0) { lm[g][hd] = mh; llv[g][hd] = lh; }
  __syncthreads();

  // merge 8 group-partials; thread t owns channel c=t
  int c = t, hh = c >> 5;
  float M = -INFINITY;
#pragma unroll
  for (int g2 = 0; g2 < 8; ++g2) M = fmaxf(M, lm[g2][hh]);
  float L = 0.f, o = 0.f;
#pragma unroll
  for (int g2 = 0; g2 < 8; ++g2) {
    float e2 = __expf(lm[g2][hh] - M);
    L = fmaf(llv[g2][hh], e2, L);
    o = fmaf(lacc[g2][c], e2, o);
  }
  pacc[(size_t)nb*HDIM + c] = o;
  if ((c & 31) == 0) {
    pm[nb*NHEADS + hh] = M;
    pl[nb*NHEADS + hh] = L;
  }
}

// ---------------- GATv2 attention, stage 2: merge + residual + LayerNorm -----
__global__ __launch_bounds__(256) void attn_merge(
    const float* __restrict__ pm, const float* __restrict__ pl,
    const float* __restrict__ pacc,
    const float* __restrict__ gb, const float* __restrict__ lng,
    const float* __restrict__ lnb,
    const float* __restrict__ h_in,
    const float* __restrict__ x, const float* __restrict__ embW,
    const float* __restrict__ embb,
    float* __restrict__ h_out) {
  int n = blockIdx.x, t = threadIdx.x;
  int c = t, hh = c >> 5;
  float M = -INFINITY;
#pragma unroll
  for (int s = 0; s < SEG; ++s) M = fmaxf(M, pm[(n*SEG + s)*NHEADS + hh]);
  float L = 0.f, o = 0.f;
#pragma unroll
  for (int s = 0; s < SEG; ++s) {
    float e2 = __expf(pm[(n*SEG + s)*NHEADS + hh] - M);
    L = fmaf(pl[(n*SEG + s)*NHEADS + hh], e2, L);
    o = fmaf(pacc[(size_t)(n*SEG + s)*HDIM + c], e2, o);
  }
  float hi = h_in ? h_in[(size_t)n*HDIM + c] : fmaf(x[n], embW[c], embb[c]);
  float val = o / L + gb[c] + hi;

  // LayerNorm over 256 channels + relu
  float s1 = val, s2 = val * val;
#pragma unroll
  for (int off = 1; off < 64; off <<= 1) {
    s1 += __shfl_xor(s1, off);
    s2 += __shfl_xor(s2, off);
  }
  __shared__ float rs1[4], rs2[4];
  if ((t & 63) == 0) { rs1[t >> 6] = s1; rs2[t >> 6] = s2; }
  __syncthreads();
  float S1 = rs1[0] + rs1[1] + rs1[2] + rs1[3];
  float S2 = rs2[0] + rs2[1] + rs2[2] + rs2[3];
  float mu = S1 * (1.f/HDIM);
  float var = S2 * (1.f/HDIM) - mu * mu;
  float y = (val - mu) * rsqrtf(var + 1e-5f);
  y = fmaf(y, lng[c], lnb[c]);
  h_out[(size_t)n*HDIM + c] = fmaxf(y, 0.f);
}

// ---------------- all-pairs policy MLP via MFMA (f16 A/B, no LDS) ------------
// A,B consumed as packed f16; q = relu(A[i]+B[j]) via packed-f16 add/max,
// fed straight to MFMA (no conversions).
__global__ __launch_bounds__(256, 4) void pair_mfma_kernel(
    const unsigned short* __restrict__ Ah, const unsigned short* __restrict__ Bh,
    const unsigned short* __restrict__ W2h,
    const float* __restrict__ b2, const float* __restrict__ W3,
    const float* __restrict__ b3, float* __restrict__ out, int N) {
  // triangular tile decode: tiles (ti, tj), tj >= ti, 32x32 tiles of 16
  int bb = blockIdx.x;
  int half = bb & 1;
  int b = bb >> 1, ti = 0, rem = 32;
  while (b >= rem) { b -= rem; ti++; rem--; }
  int tj = ti + b;
  int i0 = ti * 16 + half * 8;     // block's 8 i-rows
  int j0 = tj * 16;

  int t = threadIdx.x;
  int w = t >> 6, l = t & 63;
  int quad = l >> 4, nl = l & 15;

  float b2v[8], w3v[8];
#pragma unroll
  for (int nt = 0; nt < 8; ++nt) {
    b2v[nt] = b2[nt*16 + nl];
    w3v[nt] = W3[nt*16 + nl];
  }

  const unsigned short* Brow = Bh + (size_t)(j0 + nl) * HDIM;   // lane's B row
  const unsigned short* Arow0 = Ah + (size_t)(i0 + w*2) * HDIM; // wave's first A row
  const _Float16 zero = (_Float16)0.f;

  f32x4 acc[2][8];
#pragma unroll
  for (int a2 = 0; a2 < 2; ++a2)
#pragma unroll
    for (int nt = 0; nt < 8; ++nt) acc[a2][nt] = (f32x4){0.f,0.f,0.f,0.f};

  for (int c = 0; c < 8; ++c) {       // K chunks of 32; lane covers 8 k's
    int kb = c*32 + quad*8;
    f16x8 bv = *(const f16x8*)(Brow + kb);

    f16x8 afrag[2];
#pragma unroll
    for (int a2 = 0; a2 < 2; ++a2) {
      f16x8 av = *(const f16x8*)(Arow0 + (size_t)a2*HDIM + kb);
      union { f16x8 v8; _Float16 h[8]; } u;
      u.v8 = av + bv;                 // v_pk_add_f16
#pragma unroll
      for (int j = 0; j < 8; ++j)     // relu -> v_pk_max_f16
        u.h[j] = u.h[j] > zero ? u.h[j] : zero;
      afrag[a2] = u.v8;
    }

#pragma unroll
    for (int nt = 0; nt < 8; ++nt) {
      f16x8 bfrag = *(const f16x8*)(W2h + (size_t)(((c*8 + nt)*64 + l) * 8));
#pragma unroll
      for (int a2 = 0; a2 < 2; ++a2)
        acc[a2][nt] = __builtin_amdgcn_mfma_f32_16x16x32_f16(
            afrag[a2], bfrag, acc[a2][nt], 0, 0, 0);
    }
  }

  float b3v = b3[0];
#pragma unroll
  for (int a2 = 0; a2 < 2; ++a2) {
    int i = i0 + w*2 + a2;
#pragma unroll
    for (int r = 0; r < 4; ++r) {
      float s = 0.f;
#pragma unroll
      for (int nt = 0; nt < 8; ++nt)
        s = fmaf(fmaxf(acc[a2][nt][r] + b2v[nt], 0.f), w3v[nt], s);
      s += __shfl_xor(s, 1);
      s += __shfl_xor(s, 2);
      s += __shfl_xor(s, 4);
      s += __shfl_xor(s, 8);
      if (nl == 0) {
        int j = j0 + quad*4 + r;
        if (i < j)
          out[(size_t)i*(2*N - i - 1)/2 + (j - i - 1)] = s + b3v;
      }
    }
  }
}

// ---------------- value head, stage 1: pooling partials (32 blocks) ----------
__global__ __launch_bounds__(256) void pool_kernel(
    const float* __restrict__ h, float* __restrict__ psums,
    float* __restrict__ pmaxs) {
  int g = blockIdx.x, t = threadIdx.x;
  float s = 0.f, m = -INFINITY;
#pragma unroll
  for (int r = 0; r < 16; ++r) {
    float v = h[(size_t)(g*16 + r)*HDIM + t];
    s += v; m = fmaxf(m, v);
  }
  psums[g*HDIM + t] = s;
  pmaxs[g*HDIM + t] = m;
}

// ---------------- value head, stage 2: partial matvec (32 blocks) ------------
__global__ __launch_bounds__(256) void value1_kernel(
    const float* __restrict__ psums, const float* __restrict__ pmaxs,
    const float* __restrict__ v1W, float* __restrict__ vpart, int N) {
  int b = blockIdx.x, t = threadIdx.x;
  int k0 = b * 16;
  int kk = t >> 4, g = t & 15;
  __shared__ float repr16[16];
  int k = k0 + kk;
  float v;
  if (k < HDIM) {
    v = psums[g*HDIM + k] + psums[(g + 16)*HDIM + k];
    v += __shfl_xor(v, 1); v += __shfl_xor(v, 2);
    v += __shfl_xor(v, 4); v += __shfl_xor(v, 8);
    if (g == 0) repr16[kk] = v / (float)N;
  } else {
    int kc = k - HDIM;
    v = fmaxf(pmaxs[g*HDIM + kc], pmaxs[(g + 16)*HDIM + kc]);
    v = fmaxf(v, __shfl_xor(v, 1)); v = fmaxf(v, __shfl_xor(v, 2));
    v = fmaxf(v, __shfl_xor(v, 4)); v = fmaxf(v, __shfl_xor(v, 8));
    if (g == 0) repr16[kk] = v;
  }
  __syncthreads();
  float pv = 0.f;
#pragma unroll
  for (int q = 0; q < 16; ++q)
    pv = fmaf(repr16[q], v1W[(size_t)(k0 + q)*HDIM + t], pv);
  vpart[b*HDIM + t] = pv;
}

// ---------------- value head, stage 3: finish (1 block) ----------------------
__global__ __launch_bounds__(256) void value2_kernel(
    const float* __restrict__ vpart, const float* __restrict__ v1b,
    const float* __restrict__ v2W, const float* __restrict__ v2b,
    float* __restrict__ out) {
  int t = threadIdx.x;
  float a = 0.f;
#pragma unroll
  for (int g = 0; g < 32; ++g) a += vpart[g*HDIM + t];
  a = fmaxf(a + v1b[t], 0.f);
  float pv = a * v2W[t];
#pragma unroll
  for (int off = 1; off < 64; off <<= 1) pv += __shfl_xor(pv, off);
  __shared__ float wsum[4];
  if ((t & 63) == 0) wsum[t >> 6] = pv;
  __syncthreads();
  if (t == 0) out[0] = wsum[0] + wsum[1] + wsum[2] + wsum[3] + v2b[0];
}

// ---------------- host orchestration ----------------
extern "C" void kernel_launch(void* const* d_in, const int* in_sizes, int n_in,
                              void* d_out, int out_size, void* d_ws, size_t ws_size,
                              hipStream_t stream) {
  const float* x    = (const float*)d_in[0];
  const int*   ei   = (const int*)  d_in[1];
  const float* ea   = (const float*)d_in[2];
  const float* embW = (const float*)d_in[3];
  const float* embb = (const float*)d_in[4];
  const float* Wl   = (const float*)d_in[5];
  const float* bl   = (const float*)d_in[6];
  const float* Wr   = (const float*)d_in[7];
  const float* br   = (const float*)d_in[8];
  const float* We   = (const float*)d_in[9];
  const float* att  = (const float*)d_in[10];
  const float* gb   = (const float*)d_in[11];
  const float* lng  = (const float*)d_in[12];
  const float* lnb  = (const float*)d_in[13];
  const float* p1W  = (const float*)d_in[14];
  const float* p1b  = (const float*)d_in[15];
  const float* p2W  = (const float*)d_in[16];
  const float* p2b  = (const float*)d_in[17];
  const float* p3W  = (const float*)d_in[18];
  const float* p3b  = (const float*)d_in[19];
  const float* v1W  = (const float*)d_in[20];
  const float* v1b  = (const float*)d_in[21];
  const float* v2W  = (const float*)d_in[22];
  const float* v2b  = (const float*)d_in[23];
  const float* coup = (const float*)d_in[24];

  int N = in_sizes[0];         // 512
  int E = in_sizes[2] / 3;     // 260000
  float* out = (float*)d_out;
  size_t P = (size_t)N*(N-1)/2;

  // ---- workspace carve (long-lived region first) ----
  char* w = (char*)d_ws;
  int*    rowp = (int*)   (w + 0);        // 2052 -> pad 2560
  float*  plS  = (float*) (w + 2560);     // 32768 -> 35328
  float*  plM  = (float*) (w + 35328);    // 32768 -> 68096
  float*  vprt = (float*) (w + 68096);    // 32768 -> 100864 -> pad 101120
  float4* csr  = (float4*)(w + 101120);   // (E+N)*16
  size_t csr_end = 101120 + (size_t)(E + N) * 16;
  csr_end = (csr_end + 255) & ~(size_t)255;
  float* hA  = (float*)(w + csr_end);
  float* hB  = hA  + (size_t)N*HDIM;
  float* xrb = hB  + (size_t)N*HDIM;
  unsigned short* xlh = (unsigned short*)(xrb + (size_t)N*HDIM);  // N*256 f16
  unsigned short* Abh = xlh + (size_t)N*HDIM;                     // N*256 f16
  unsigned short* Bbh = Abh + (size_t)N*HDIM;                     // N*256 f16
  unsigned short* W2h = Bbh + (size_t)N*HDIM;                     // 32768 f16
  unsigned short* Whall = W2h + 32768;                            // 10*65536 f16
  size_t ubase = ((size_t)((char*)(Whall + 10*65536) - w) + 255) & ~(size_t)255;

  // ---- union region: CSR-build scratch (phase 1) / attn partials (phase 2) --
  char* U = w + ubase;
  int*    pcnt = (int*)   (U + 0);        // NB*512*4          = 524288
  float*  psum = (float*) (U + 524288);   // 3*NB*512*4        = 1572864 -> 2097152
  int*    pcol = (int*)   (U + 2097152);  // 2*NB*512*4        = 1048576 -> 3145728
  int*    pbase= (int*)   (U + 3145728);  // NB*512*4          = 524288  -> 3670016
  int*    cnt  = (int*)   (U + 3670016);  // 2048
  float*  sred = (float*) (U + 3672064);  // 6144
  int*    dred = (int*)   (U + 3678208);  // 4096
  // phase 2 overlay (CSR scratch dead after scatter2):
  float*  pmv  = (float*) (U + 0);        // N*SEG*8*4   = 65536
  float*  plv  = (float*) (U + 65536);    // 65536
  float*  pacc = (float*) (U + 131072);   // N*SEG*256*4 = 2097152

  int CH = (E + NB - 1) / NB;
  edge_part<<<NB, 256, 0, stream>>>(ei, ea, E, CH, pcnt, psum, pcol);
  red_kernel<<<12, 256, 0, stream>>>(pcnt, psum, pcol, cnt, sred, dred, pbase);
  scan2<<<1, 512, 0, stream>>>(cnt, sred, dred, N, rowp, csr, coup, out + P + 1);
  scatter2<<<NB, 256, 0, stream>>>(ei, ea, E, CH, rowp, pbase, csr);
  w_prep_all<<<2688, 256, 0, stream>>>(Wl, Wr, p1W, p2W, Whall, W2h);

  float* hin = nullptr;        // layer 0: h computed on the fly from x
  float* hout = hB;
  for (int l = 0; l < 4; ++l) {
    dual_gemm_mfma<<<dim3(8, 32), 256, 0, stream>>>(hin, x, embW, embb,
        Whall + (size_t)l*65536, Whall + (size_t)(4 + l)*65536,
        bl + l*HDIM, br + l*HDIM,
        (float*)nullptr, xlh, xrb, (unsigned short*)nullptr);
    attn_gather<<<N*SEG, 256, 0, stream>>>(xlh, xrb, csr, rowp,
        We + (size_t)l*3*HDIM, att + (size_t)l*HDIM, pmv, plv, pacc);
    attn_merge<<<N, 256, 0, stream>>>(pmv, plv, pacc,
        gb + (size_t)l*HDIM, lng + (size_t)l*HDIM, lnb + (size_t)l*HDIM,
        hin, x, embW, embb, hout);
    hin = hout;
    hout = (hout == hB) ? hA : hB;
  }
  // after 4 layers: hin points at final h

  // pairs head: A = h@p1W[:256]+b1, B = h@p1W[256:]  (f16 outputs only)
  dual_gemm_mfma<<<dim3(8, 32), 256, 0, stream>>>(hin, x, embW, embb,
      Whall + (size_t)8*65536, Whall + (size_t)9*65536,
      p1b, (const float*)nullptr,
      (float*)nullptr, Abh, (float*)nullptr, Bbh);

  pair_mfma_kernel<<<1056, 256, 0, stream>>>(Abh, Bbh, W2h, p2b, p3W, p3b, out, N);

  pool_kernel<<<32, 256, 0, stream>>>(hin, plS, plM);
  value1_kernel<<<32, 256, 0, stream>>>(plS, plM, v1W, vprt, N);
  value2_kernel<<<1, 256, 0, stream>>>(vprt, v1b, v2W, v2b, out + P);
}